// Round 1
// baseline (2134.024 us; speedup 1.0000x reference)
//
#include <hip/hip_runtime.h>
#include <hip/hip_bf16.h>

#define DD 128
#define ROWS 16

// ---------------------------------------------------------------------------
// Fused edge MLP: e_out = e_in + MLP(concat[e_in, n[src], n[dst]])
// block = 128 threads (thread = output column), 16 edge rows per block.
// ---------------------------------------------------------------------------
__global__ __launch_bounds__(128)
void edge_mlp(const float* __restrict__ e_in,
              const float* __restrict__ nf,
              const int* __restrict__ src,
              const int* __restrict__ dst,
              const float* __restrict__ W1,   // [384,128]
              const float* __restrict__ b1,
              const float* __restrict__ g1,
              const float* __restrict__ be1,
              const float* __restrict__ W2,   // [128,128]
              const float* __restrict__ b2,
              float* __restrict__ e_out)
{
    __shared__ __align__(16) float in_lds[ROWS][3*DD];
    __shared__ __align__(16) float sil[ROWS][DD];
    __shared__ float red[2][ROWS][2];
    const int tid  = threadIdx.x;
    const int lane = tid & 63, wid = tid >> 6;
    const long base = (long)blockIdx.x * ROWS;

    #pragma unroll
    for (int r = 0; r < ROWS; ++r) {
        const long erow = base + r;
        const int sI = src[erow];
        const int dI = dst[erow];
        in_lds[r][tid]        = e_in[erow*DD + tid];
        in_lds[r][DD + tid]   = nf[(long)sI*DD + tid];
        in_lds[r][2*DD + tid] = nf[(long)dI*DD + tid];
    }
    __syncthreads();

    const float b1v = b1[tid], g1v = g1[tid], be1v = be1[tid], b2v = b2[tid];

    float acc[ROWS];
    #pragma unroll
    for (int r = 0; r < ROWS; ++r) acc[r] = 0.f;

    for (int k = 0; k < 3*DD; k += 4) {
        const float w0 = W1[(k+0)*DD + tid];
        const float w1 = W1[(k+1)*DD + tid];
        const float w2 = W1[(k+2)*DD + tid];
        const float w3 = W1[(k+3)*DD + tid];
        #pragma unroll
        for (int r = 0; r < ROWS; ++r) {
            const float4 iv = *(const float4*)&in_lds[r][k];
            acc[r] = fmaf(iv.x, w0, fmaf(iv.y, w1, fmaf(iv.z, w2, fmaf(iv.w, w3, acc[r]))));
        }
    }

    // bias + LayerNorm stats (cross-thread over the 128 columns)
    #pragma unroll
    for (int r = 0; r < ROWS; ++r) {
        const float h = acc[r] + b1v;
        acc[r] = h;
        float sv = h, qv = h*h;
        #pragma unroll
        for (int off = 32; off >= 1; off >>= 1) {
            sv += __shfl_xor(sv, off);
            qv += __shfl_xor(qv, off);
        }
        if (lane == 0) { red[wid][r][0] = sv; red[wid][r][1] = qv; }
    }
    __syncthreads();
    #pragma unroll
    for (int r = 0; r < ROWS; ++r) {
        const float S  = red[0][r][0] + red[1][r][0];
        const float Q  = red[0][r][1] + red[1][r][1];
        const float mu = S * (1.0f/DD);
        const float var = Q * (1.0f/DD) - mu*mu;
        const float inv = rsqrtf(var + 1e-5f);
        const float hn = (acc[r] - mu) * inv * g1v + be1v;
        sil[r][tid] = hn / (1.0f + __expf(-hn));   // SiLU
    }
    __syncthreads();

    float acc2[ROWS];
    #pragma unroll
    for (int r = 0; r < ROWS; ++r) acc2[r] = 0.f;

    for (int k = 0; k < DD; k += 4) {
        const float w0 = W2[(k+0)*DD + tid];
        const float w1 = W2[(k+1)*DD + tid];
        const float w2 = W2[(k+2)*DD + tid];
        const float w3 = W2[(k+3)*DD + tid];
        #pragma unroll
        for (int r = 0; r < ROWS; ++r) {
            const float4 sv4 = *(const float4*)&sil[r][k];
            acc2[r] = fmaf(sv4.x, w0, fmaf(sv4.y, w1, fmaf(sv4.z, w2, fmaf(sv4.w, w3, acc2[r]))));
        }
    }

    #pragma unroll
    for (int r = 0; r < ROWS; ++r) {
        const long erow = base + r;
        e_out[erow*DD + tid] = in_lds[r][tid] + acc2[r] + b2v;
    }
}

// ---------------------------------------------------------------------------
// Fused node MLP: n_out = n_in + MLP(concat[n_in, agg])
// ---------------------------------------------------------------------------
__global__ __launch_bounds__(128)
void node_mlp(const float* __restrict__ n_in,
              const float* __restrict__ agg,
              const float* __restrict__ W1,   // [256,128]
              const float* __restrict__ b1,
              const float* __restrict__ g1,
              const float* __restrict__ be1,
              const float* __restrict__ W2,   // [128,128]
              const float* __restrict__ b2,
              float* __restrict__ n_out)
{
    __shared__ __align__(16) float in_lds[ROWS][2*DD];
    __shared__ __align__(16) float sil[ROWS][DD];
    __shared__ float red[2][ROWS][2];
    const int tid  = threadIdx.x;
    const int lane = tid & 63, wid = tid >> 6;
    const long base = (long)blockIdx.x * ROWS;

    #pragma unroll
    for (int r = 0; r < ROWS; ++r) {
        const long row = base + r;
        in_lds[r][tid]      = n_in[row*DD + tid];
        in_lds[r][DD + tid] = agg[row*DD + tid];
    }
    __syncthreads();

    const float b1v = b1[tid], g1v = g1[tid], be1v = be1[tid], b2v = b2[tid];

    float acc[ROWS];
    #pragma unroll
    for (int r = 0; r < ROWS; ++r) acc[r] = 0.f;

    for (int k = 0; k < 2*DD; k += 4) {
        const float w0 = W1[(k+0)*DD + tid];
        const float w1 = W1[(k+1)*DD + tid];
        const float w2 = W1[(k+2)*DD + tid];
        const float w3 = W1[(k+3)*DD + tid];
        #pragma unroll
        for (int r = 0; r < ROWS; ++r) {
            const float4 iv = *(const float4*)&in_lds[r][k];
            acc[r] = fmaf(iv.x, w0, fmaf(iv.y, w1, fmaf(iv.z, w2, fmaf(iv.w, w3, acc[r]))));
        }
    }

    #pragma unroll
    for (int r = 0; r < ROWS; ++r) {
        const float h = acc[r] + b1v;
        acc[r] = h;
        float sv = h, qv = h*h;
        #pragma unroll
        for (int off = 32; off >= 1; off >>= 1) {
            sv += __shfl_xor(sv, off);
            qv += __shfl_xor(qv, off);
        }
        if (lane == 0) { red[wid][r][0] = sv; red[wid][r][1] = qv; }
    }
    __syncthreads();
    #pragma unroll
    for (int r = 0; r < ROWS; ++r) {
        const float S  = red[0][r][0] + red[1][r][0];
        const float Q  = red[0][r][1] + red[1][r][1];
        const float mu = S * (1.0f/DD);
        const float var = Q * (1.0f/DD) - mu*mu;
        const float inv = rsqrtf(var + 1e-5f);
        const float hn = (acc[r] - mu) * inv * g1v + be1v;
        sil[r][tid] = hn / (1.0f + __expf(-hn));
    }
    __syncthreads();

    float acc2[ROWS];
    #pragma unroll
    for (int r = 0; r < ROWS; ++r) acc2[r] = 0.f;

    for (int k = 0; k < DD; k += 4) {
        const float w0 = W2[(k+0)*DD + tid];
        const float w1 = W2[(k+1)*DD + tid];
        const float w2 = W2[(k+2)*DD + tid];
        const float w3 = W2[(k+3)*DD + tid];
        #pragma unroll
        for (int r = 0; r < ROWS; ++r) {
            const float4 sv4 = *(const float4*)&sil[r][k];
            acc2[r] = fmaf(sv4.x, w0, fmaf(sv4.y, w1, fmaf(sv4.z, w2, fmaf(sv4.w, w3, acc2[r]))));
        }
    }

    #pragma unroll
    for (int r = 0; r < ROWS; ++r) {
        const long row = base + r;
        n_out[row*DD + tid] = in_lds[r][tid] + acc2[r] + b2v;
    }
}

// ---------------------------------------------------------------------------
// Scatter-add: agg[dst[e]] += e_new[e]   (fp32 atomics)
// ---------------------------------------------------------------------------
__global__ void scatter_add(const float* __restrict__ e,
                            const int* __restrict__ dst,
                            float* __restrict__ agg, int total)
{
    int i = blockIdx.x * blockDim.x + threadIdx.x;
    const int stride = gridDim.x * blockDim.x;
    for (; i < total; i += stride) {
        const int edge = i >> 7;
        const int c = i & (DD - 1);
        atomicAdd(&agg[(long)dst[edge]*DD + c], e[i]);
    }
}

extern "C" void kernel_launch(void* const* d_in, const int* in_sizes, int n_in,
                              void* d_out, int out_size, void* d_ws, size_t ws_size,
                              hipStream_t stream) {
    const float* node_feat = (const float*)d_in[0];
    const float* edge_attr = (const float*)d_in[1];
    const int*   edge_index= (const int*)d_in[2];
    const float* eW1 = (const float*)d_in[3];
    const float* eb1 = (const float*)d_in[4];
    const float* eg1 = (const float*)d_in[5];
    const float* ebe1= (const float*)d_in[6];
    const float* eW2 = (const float*)d_in[7];
    const float* eb2 = (const float*)d_in[8];
    const float* nW1 = (const float*)d_in[9];
    const float* nb1 = (const float*)d_in[10];
    const float* ng1 = (const float*)d_in[11];
    const float* nbe1= (const float*)d_in[12];
    const float* nW2 = (const float*)d_in[13];
    const float* nb2 = (const float*)d_in[14];

    const int N = 50000, E = 256000;
    const int* src  = edge_index;
    const int* dstI = edge_index + E;

    float* out_n = (float*)d_out;                    // [N,128]
    float* out_e = (float*)d_out + (size_t)N * DD;   // [E,128]
    float* agg   = (float*)d_ws;                     // [N,128] scratch

    // ---- layer 0 ----
    edge_mlp<<<E/ROWS, 128, 0, stream>>>(edge_attr, node_feat, src, dstI,
        eW1, eb1, eg1, ebe1, eW2, eb2, out_e);
    hipMemsetAsync(agg, 0, (size_t)N * DD * sizeof(float), stream);
    scatter_add<<<2048, 256, 0, stream>>>(out_e, dstI, agg, E * DD);
    node_mlp<<<N/ROWS, 128, 0, stream>>>(node_feat, agg,
        nW1, nb1, ng1, nbe1, nW2, nb2, out_n);

    // ---- layer 1 (in-place on d_out regions) ----
    edge_mlp<<<E/ROWS, 128, 0, stream>>>(out_e, out_n, src, dstI,
        eW1 + 3*DD*DD, eb1 + DD, eg1 + DD, ebe1 + DD, eW2 + DD*DD, eb2 + DD, out_e);
    hipMemsetAsync(agg, 0, (size_t)N * DD * sizeof(float), stream);
    scatter_add<<<2048, 256, 0, stream>>>(out_e, dstI, agg, E * DD);
    node_mlp<<<N/ROWS, 128, 0, stream>>>(out_n, agg,
        nW1 + 2*DD*DD, nb1 + DD, ng1 + DD, nbe1 + DD, nW2 + DD*DD, nb2 + DD, out_n);
}

// Round 2
// 1440.583 us; speedup vs baseline: 1.4814x; 1.4814x over previous
//
#include <hip/hip_runtime.h>
#include <hip/hip_bf16.h>

typedef float f32x4 __attribute__((ext_vector_type(4)));
typedef __bf16 v8bf __attribute__((ext_vector_type(8)));

#define DD 128
#define EDGES 256000
#define NODES 50000

__device__ __forceinline__ unsigned short f2bf(float f) {
    union { float f; unsigned u; } v; v.f = f;
    unsigned r = v.u + 0x7fffu + ((v.u >> 16) & 1u);
    return (unsigned short)(r >> 16);
}

// ---------------------------------------------------------------------------
// Weight prep: fp32 -> bf16, packed in MFMA B-fragment order.
// Packed layout for a [K][128] matrix: dst[((kt*8+ct)*64+l)*8 + j] =
//   bf16(W[(kt*32 + (l>>4)*8 + j)*128 + ct*16 + (l&15)])
// ws offsets (ushorts): e1: l*49152 | e2: 98304+l*16384 |
//                       n1: 131072+l*32768 | n2: 196608+l*16384
// ---------------------------------------------------------------------------
__global__ __launch_bounds__(512)
void pack_weights(const float* __restrict__ eW1, const float* __restrict__ eW2,
                  const float* __restrict__ nW1, const float* __restrict__ nW2,
                  unsigned short* __restrict__ wp)
{
    const int b = blockIdx.x;            // 0..55
    const int layer = b / 28;
    const int u = b % 28;
    const float* W; int kt; unsigned short* dst;
    if (u < 12)      { W = eW1 + layer*384*128; kt = u;      dst = wp + layer*49152; }
    else if (u < 16) { W = eW2 + layer*128*128; kt = u - 12; dst = wp + 98304 + layer*16384; }
    else if (u < 24) { W = nW1 + layer*256*128; kt = u - 16; dst = wp + 131072 + layer*32768; }
    else             { W = nW2 + layer*128*128; kt = u - 24; dst = wp + 196608 + layer*16384; }
    const int t = threadIdx.x;           // 512 = 8 ct * 64 lanes
    const int ct = t >> 6, l = t & 63;
    #pragma unroll
    for (int j = 0; j < 8; ++j) {
        const int k = kt*32 + ((l >> 4) * 8) + j;
        const int c = ct*16 + (l & 15);
        dst[((kt*8 + ct)*64 + l)*8 + j] = f2bf(W[k*128 + c]);
    }
}

// ---------------------------------------------------------------------------
// Edge MLP (MFMA): e_out = e_in + MLP(concat[e_in, n[src], n[dst]])
// 256 threads, 64 rows/block, wave tile 32 rows x 64 cols.
// ---------------------------------------------------------------------------
__global__ __launch_bounds__(256)
void edge_mlp(const float* e_in, const float* __restrict__ nf,
              const int* __restrict__ src, const int* __restrict__ dst,
              const unsigned short* __restrict__ Wp1,
              const float* __restrict__ b1, const float* __restrict__ g1,
              const float* __restrict__ be1,
              const unsigned short* __restrict__ Wp2,
              const float* __restrict__ b2, float* e_out)
{
    __shared__ unsigned short Ae[64][392];   // 384 + 8 pad
    __shared__ unsigned short Sl[64][136];   // 128 + 8 pad
    __shared__ float red[4][32][2];
    __shared__ int gidx[2][64];
    const int tid = threadIdx.x;
    const long base = (long)blockIdx.x * 64;

    if (tid < 64)       gidx[0][tid]      = src[base + tid];
    else if (tid < 128) gidx[1][tid - 64] = dst[base + tid - 64];
    __syncthreads();

    // ---- stage A tile (fp32 -> bf16) ----
    #pragma unroll
    for (int it = 0; it < 24; ++it) {
        const int i = tid + it*256;          // 6144 float4 total
        const int row = i / 96;
        const int c = (i - row*96) * 4;
        const float* p;
        if (c < 128)      p = &e_in[(base + row)*DD + c];
        else if (c < 256) p = &nf[(long)gidx[0][row]*DD + (c - 128)];
        else              p = &nf[(long)gidx[1][row]*DD + (c - 256)];
        const float4 v = *(const float4*)p;
        ushort4 o; o.x = f2bf(v.x); o.y = f2bf(v.y); o.z = f2bf(v.z); o.w = f2bf(v.w);
        *(ushort4*)&Ae[row][c] = o;
    }
    __syncthreads();

    const int lane = tid & 63, w = tid >> 6;
    const int wr = w >> 1, wc = w & 1;
    const int R0 = wr*32, C0 = wc*64;
    const int lg = lane >> 4, ll = lane & 15;

    float b1v[4], g1v[4], be1v[4], b2v[4];
    #pragma unroll
    for (int ct = 0; ct < 4; ++ct) {
        const int c = C0 + ct*16 + ll;
        b1v[ct] = b1[c]; g1v[ct] = g1[c]; be1v[ct] = be1[c]; b2v[ct] = b2[c];
    }

    // ---- GEMM1: [64x384] @ [384x128] ----
    f32x4 acc[2][4] = {};
    #pragma unroll
    for (int kt = 0; kt < 12; ++kt) {
        const v8bf a0 = *(const v8bf*)&Ae[R0 + ll][kt*32 + lg*8];
        const v8bf a1 = *(const v8bf*)&Ae[R0 + 16 + ll][kt*32 + lg*8];
        #pragma unroll
        for (int ct = 0; ct < 4; ++ct) {
            const v8bf b = *(const v8bf*)&Wp1[((kt*8 + wc*4 + ct)*64 + lane)*8];
            acc[0][ct] = __builtin_amdgcn_mfma_f32_16x16x32_bf16(a0, b, acc[0][ct], 0, 0, 0);
            acc[1][ct] = __builtin_amdgcn_mfma_f32_16x16x32_bf16(a1, b, acc[1][ct], 0, 0, 0);
        }
    }

    // ---- bias + LN stats ----
    f32x4 s[2], q[2];
    #pragma unroll
    for (int rt = 0; rt < 2; ++rt) {
        #pragma unroll
        for (int ct = 0; ct < 4; ++ct) acc[rt][ct] += b1v[ct];
        s[rt] = acc[rt][0] + acc[rt][1] + acc[rt][2] + acc[rt][3];
        q[rt] = acc[rt][0]*acc[rt][0] + acc[rt][1]*acc[rt][1]
              + acc[rt][2]*acc[rt][2] + acc[rt][3]*acc[rt][3];
    }
    #pragma unroll
    for (int off = 1; off <= 8; off <<= 1) {
        #pragma unroll
        for (int rt = 0; rt < 2; ++rt) {
            #pragma unroll
            for (int j = 0; j < 4; ++j) {
                s[rt][j] += __shfl_xor(s[rt][j], off);
                q[rt][j] += __shfl_xor(q[rt][j], off);
            }
        }
    }
    if (ll == 0) {
        #pragma unroll
        for (int rt = 0; rt < 2; ++rt)
            #pragma unroll
            for (int j = 0; j < 4; ++j) {
                red[w][rt*16 + lg*4 + j][0] = s[rt][j];
                red[w][rt*16 + lg*4 + j][1] = q[rt][j];
            }
    }
    __syncthreads();

    // ---- LN + SiLU -> Sl (bf16) ----
    #pragma unroll
    for (int rt = 0; rt < 2; ++rt) {
        #pragma unroll
        for (int j = 0; j < 4; ++j) {
            const int lr = rt*16 + lg*4 + j;
            const float S = red[2*wr][lr][0] + red[2*wr + 1][lr][0];
            const float Q = red[2*wr][lr][1] + red[2*wr + 1][lr][1];
            const float mu = S * (1.0f/DD);
            const float var = Q * (1.0f/DD) - mu*mu;
            const float inv = rsqrtf(var + 1e-5f);
            #pragma unroll
            for (int ct = 0; ct < 4; ++ct) {
                const float hn = (acc[rt][ct][j] - mu) * inv * g1v[ct] + be1v[ct];
                const float sv = hn / (1.0f + __expf(-hn));
                Sl[R0 + lr][C0 + ct*16 + ll] = f2bf(sv);
            }
        }
    }
    __syncthreads();

    // ---- GEMM2: [64x128] @ [128x128] ----
    f32x4 acc2[2][4] = {};
    #pragma unroll
    for (int kt = 0; kt < 4; ++kt) {
        const v8bf a0 = *(const v8bf*)&Sl[R0 + ll][kt*32 + lg*8];
        const v8bf a1 = *(const v8bf*)&Sl[R0 + 16 + ll][kt*32 + lg*8];
        #pragma unroll
        for (int ct = 0; ct < 4; ++ct) {
            const v8bf b = *(const v8bf*)&Wp2[((kt*8 + wc*4 + ct)*64 + lane)*8];
            acc2[0][ct] = __builtin_amdgcn_mfma_f32_16x16x32_bf16(a0, b, acc2[0][ct], 0, 0, 0);
            acc2[1][ct] = __builtin_amdgcn_mfma_f32_16x16x32_bf16(a1, b, acc2[1][ct], 0, 0, 0);
        }
    }

    // ---- residual (fp32 re-read) + store ----
    #pragma unroll
    for (int rt = 0; rt < 2; ++rt)
        #pragma unroll
        for (int ct = 0; ct < 4; ++ct)
            #pragma unroll
            for (int j = 0; j < 4; ++j) {
                const long grow = base + R0 + rt*16 + lg*4 + j;
                const int ccol = C0 + ct*16 + ll;
                e_out[grow*DD + ccol] = e_in[grow*DD + ccol] + acc2[rt][ct][j] + b2v[ct];
            }
}

// ---------------------------------------------------------------------------
// Node MLP (MFMA): n_out = n_in + MLP(concat[n_in, agg])
// ---------------------------------------------------------------------------
__global__ __launch_bounds__(256)
void node_mlp(const float* n_in, const float* __restrict__ agg,
              const unsigned short* __restrict__ Wp1,
              const float* __restrict__ b1, const float* __restrict__ g1,
              const float* __restrict__ be1,
              const unsigned short* __restrict__ Wp2,
              const float* __restrict__ b2, float* n_out)
{
    __shared__ unsigned short Ae[64][264];   // 256 + 8 pad
    __shared__ unsigned short Sl[64][136];
    __shared__ float red[4][32][2];
    const int tid = threadIdx.x;
    const long base = (long)blockIdx.x * 64;

    #pragma unroll
    for (int it = 0; it < 16; ++it) {
        const int i = tid + it*256;          // 4096 float4 total
        const int row = i >> 6;
        const int c = (i & 63) * 4;
        float4 v = {0.f, 0.f, 0.f, 0.f};
        if (base + row < NODES) {
            const float* p = (c < 128) ? &n_in[(base + row)*DD + c]
                                       : &agg[(base + row)*DD + (c - 128)];
            v = *(const float4*)p;
        }
        ushort4 o; o.x = f2bf(v.x); o.y = f2bf(v.y); o.z = f2bf(v.z); o.w = f2bf(v.w);
        *(ushort4*)&Ae[row][c] = o;
    }
    __syncthreads();

    const int lane = tid & 63, w = tid >> 6;
    const int wr = w >> 1, wc = w & 1;
    const int R0 = wr*32, C0 = wc*64;
    const int lg = lane >> 4, ll = lane & 15;

    float b1v[4], g1v[4], be1v[4], b2v[4];
    #pragma unroll
    for (int ct = 0; ct < 4; ++ct) {
        const int c = C0 + ct*16 + ll;
        b1v[ct] = b1[c]; g1v[ct] = g1[c]; be1v[ct] = be1[c]; b2v[ct] = b2[c];
    }

    f32x4 acc[2][4] = {};
    #pragma unroll
    for (int kt = 0; kt < 8; ++kt) {
        const v8bf a0 = *(const v8bf*)&Ae[R0 + ll][kt*32 + lg*8];
        const v8bf a1 = *(const v8bf*)&Ae[R0 + 16 + ll][kt*32 + lg*8];
        #pragma unroll
        for (int ct = 0; ct < 4; ++ct) {
            const v8bf b = *(const v8bf*)&Wp1[((kt*8 + wc*4 + ct)*64 + lane)*8];
            acc[0][ct] = __builtin_amdgcn_mfma_f32_16x16x32_bf16(a0, b, acc[0][ct], 0, 0, 0);
            acc[1][ct] = __builtin_amdgcn_mfma_f32_16x16x32_bf16(a1, b, acc[1][ct], 0, 0, 0);
        }
    }

    f32x4 s[2], q[2];
    #pragma unroll
    for (int rt = 0; rt < 2; ++rt) {
        #pragma unroll
        for (int ct = 0; ct < 4; ++ct) acc[rt][ct] += b1v[ct];
        s[rt] = acc[rt][0] + acc[rt][1] + acc[rt][2] + acc[rt][3];
        q[rt] = acc[rt][0]*acc[rt][0] + acc[rt][1]*acc[rt][1]
              + acc[rt][2]*acc[rt][2] + acc[rt][3]*acc[rt][3];
    }
    #pragma unroll
    for (int off = 1; off <= 8; off <<= 1) {
        #pragma unroll
        for (int rt = 0; rt < 2; ++rt) {
            #pragma unroll
            for (int j = 0; j < 4; ++j) {
                s[rt][j] += __shfl_xor(s[rt][j], off);
                q[rt][j] += __shfl_xor(q[rt][j], off);
            }
        }
    }
    if (ll == 0) {
        #pragma unroll
        for (int rt = 0; rt < 2; ++rt)
            #pragma unroll
            for (int j = 0; j < 4; ++j) {
                red[w][rt*16 + lg*4 + j][0] = s[rt][j];
                red[w][rt*16 + lg*4 + j][1] = q[rt][j];
            }
    }
    __syncthreads();

    #pragma unroll
    for (int rt = 0; rt < 2; ++rt) {
        #pragma unroll
        for (int j = 0; j < 4; ++j) {
            const int lr = rt*16 + lg*4 + j;
            const float S = red[2*wr][lr][0] + red[2*wr + 1][lr][0];
            const float Q = red[2*wr][lr][1] + red[2*wr + 1][lr][1];
            const float mu = S * (1.0f/DD);
            const float var = Q * (1.0f/DD) - mu*mu;
            const float inv = rsqrtf(var + 1e-5f);
            #pragma unroll
            for (int ct = 0; ct < 4; ++ct) {
                const float hn = (acc[rt][ct][j] - mu) * inv * g1v[ct] + be1v[ct];
                const float sv = hn / (1.0f + __expf(-hn));
                Sl[R0 + lr][C0 + ct*16 + ll] = f2bf(sv);
            }
        }
    }
    __syncthreads();

    f32x4 acc2[2][4] = {};
    #pragma unroll
    for (int kt = 0; kt < 4; ++kt) {
        const v8bf a0 = *(const v8bf*)&Sl[R0 + ll][kt*32 + lg*8];
        const v8bf a1 = *(const v8bf*)&Sl[R0 + 16 + ll][kt*32 + lg*8];
        #pragma unroll
        for (int ct = 0; ct < 4; ++ct) {
            const v8bf b = *(const v8bf*)&Wp2[((kt*8 + wc*4 + ct)*64 + lane)*8];
            acc2[0][ct] = __builtin_amdgcn_mfma_f32_16x16x32_bf16(a0, b, acc2[0][ct], 0, 0, 0);
            acc2[1][ct] = __builtin_amdgcn_mfma_f32_16x16x32_bf16(a1, b, acc2[1][ct], 0, 0, 0);
        }
    }

    #pragma unroll
    for (int rt = 0; rt < 2; ++rt)
        #pragma unroll
        for (int ct = 0; ct < 4; ++ct)
            #pragma unroll
            for (int j = 0; j < 4; ++j) {
                const long grow = base + R0 + rt*16 + lg*4 + j;
                if (grow < NODES) {
                    const int ccol = C0 + ct*16 + ll;
                    n_out[grow*DD + ccol] = n_in[grow*DD + ccol] + acc2[rt][ct][j] + b2v[ct];
                }
            }
}

// ---------------------------------------------------------------------------
// Scatter-add: agg[dst[e]] += e_new[e]  (float4 read, 4 atomics)
// ---------------------------------------------------------------------------
__global__ void scatter_add(const float* __restrict__ e,
                            const int* __restrict__ dst,
                            float* __restrict__ agg, int total4)
{
    int i = blockIdx.x * blockDim.x + threadIdx.x;
    const int stride = gridDim.x * blockDim.x;
    for (; i < total4; i += stride) {
        const int edge = i >> 5;
        const int c = (i & 31) * 4;
        const float4 v = *(const float4*)&e[(long)edge*DD + c];
        float* a = &agg[(long)dst[edge]*DD + c];
        atomicAdd(a + 0, v.x); atomicAdd(a + 1, v.y);
        atomicAdd(a + 2, v.z); atomicAdd(a + 3, v.w);
    }
}

extern "C" void kernel_launch(void* const* d_in, const int* in_sizes, int n_in,
                              void* d_out, int out_size, void* d_ws, size_t ws_size,
                              hipStream_t stream) {
    const float* node_feat = (const float*)d_in[0];
    const float* edge_attr = (const float*)d_in[1];
    const int*   edge_index= (const int*)d_in[2];
    const float* eW1 = (const float*)d_in[3];
    const float* eb1 = (const float*)d_in[4];
    const float* eg1 = (const float*)d_in[5];
    const float* ebe1= (const float*)d_in[6];
    const float* eW2 = (const float*)d_in[7];
    const float* eb2 = (const float*)d_in[8];
    const float* nW1 = (const float*)d_in[9];
    const float* nb1 = (const float*)d_in[10];
    const float* ng1 = (const float*)d_in[11];
    const float* nbe1= (const float*)d_in[12];
    const float* nW2 = (const float*)d_in[13];
    const float* nb2 = (const float*)d_in[14];

    const int N = NODES, E = EDGES;
    const int* src  = edge_index;
    const int* dstI = edge_index + E;

    float* out_n = (float*)d_out;
    float* out_e = (float*)d_out + (size_t)N * DD;
    float* agg   = (float*)d_ws;                                  // 25.6 MB
    unsigned short* wp = (unsigned short*)((char*)d_ws + (size_t)N * DD * 4);

    pack_weights<<<56, 512, 0, stream>>>(eW1, eW2, nW1, nW2, wp);

    for (int l = 0; l < 2; ++l) {
        const unsigned short* eWp1 = wp + l*49152;
        const unsigned short* eWp2 = wp + 98304 + l*16384;
        const unsigned short* nWp1 = wp + 131072 + l*32768;
        const unsigned short* nWp2 = wp + 196608 + l*16384;
        const float* ein = (l == 0) ? edge_attr : out_e;
        const float* nin = (l == 0) ? node_feat : out_n;

        edge_mlp<<<E/64, 256, 0, stream>>>(ein, nin, src, dstI,
            eWp1, eb1 + l*DD, eg1 + l*DD, ebe1 + l*DD, eWp2, eb2 + l*DD, out_e);
        hipMemsetAsync(agg, 0, (size_t)N * DD * sizeof(float), stream);
        scatter_add<<<2048, 256, 0, stream>>>(out_e, dstI, agg, E*32);
        node_mlp<<<(N + 63)/64, 256, 0, stream>>>(nin, agg,
            nWp1, nb1 + l*DD, ng1 + l*DD, nbe1 + l*DD, nWp2, nb2 + l*DD, out_n);
    }
}

// Round 3
// 758.943 us; speedup vs baseline: 2.8118x; 1.8981x over previous
//
#include <hip/hip_runtime.h>
#include <hip/hip_bf16.h>

typedef float f32x4 __attribute__((ext_vector_type(4)));
typedef __bf16 v8bf __attribute__((ext_vector_type(8)));

#define DD 128
#define EDGES 256000
#define NODES 50000

__device__ __forceinline__ unsigned short f2bf(float f) {
    union { float f; unsigned u; } v; v.f = f;
    unsigned r = v.u + 0x7fffu + ((v.u >> 16) & 1u);
    return (unsigned short)(r >> 16);
}

// ---------------------------------------------------------------------------
// Weight prep: fp32 -> bf16, packed in MFMA B-fragment order.
// dst[((kt*8+ct)*64+l)*8 + j] = bf16(W[(kt*32+(l>>4)*8+j)*128 + ct*16+(l&15)])
// ---------------------------------------------------------------------------
__global__ __launch_bounds__(512)
void pack_weights(const float* __restrict__ eW1, const float* __restrict__ eW2,
                  const float* __restrict__ nW1, const float* __restrict__ nW2,
                  unsigned short* __restrict__ wp)
{
    const int b = blockIdx.x;            // 0..55
    const int layer = b / 28;
    const int u = b % 28;
    const float* W; int kt; unsigned short* dst;
    if (u < 12)      { W = eW1 + layer*384*128; kt = u;      dst = wp + layer*49152; }
    else if (u < 16) { W = eW2 + layer*128*128; kt = u - 12; dst = wp + 98304 + layer*16384; }
    else if (u < 24) { W = nW1 + layer*256*128; kt = u - 16; dst = wp + 131072 + layer*32768; }
    else             { W = nW2 + layer*128*128; kt = u - 24; dst = wp + 196608 + layer*16384; }
    const int t = threadIdx.x;           // 512 = 8 ct * 64 lanes
    const int ct = t >> 6, l = t & 63;
    #pragma unroll
    for (int j = 0; j < 8; ++j) {
        const int k = kt*32 + ((l >> 4) * 8) + j;
        const int c = ct*16 + (l & 15);
        dst[((kt*8 + ct)*64 + l)*8 + j] = f2bf(W[k*128 + c]);
    }
}

// ---------------------------------------------------------------------------
// CSR build: histogram -> scan -> placement (dst is layer-invariant)
// ---------------------------------------------------------------------------
__global__ void hist_kernel(const int* __restrict__ dst, int* __restrict__ deg)
{
    const int i = blockIdx.x * blockDim.x + threadIdx.x;
    if (i < EDGES) atomicAdd(&deg[dst[i]], 1);
}

__global__ __launch_bounds__(1024)
void scan_deg(const int* __restrict__ deg, int* __restrict__ off,
              int* __restrict__ cursor)
{
    __shared__ int ls[1024];
    const int t = threadIdx.x;
    const int C = 49;                    // 1024*49 >= 50000
    const int start = t * C;
    int s = 0;
    for (int k = 0; k < C; ++k) {
        const int idx = start + k;
        if (idx < NODES) s += deg[idx];
    }
    ls[t] = s;
    __syncthreads();
    for (int d = 1; d < 1024; d <<= 1) {
        int v = 0;
        if (t >= d) v = ls[t - d];
        __syncthreads();
        if (t >= d) ls[t] += v;
        __syncthreads();
    }
    int base = (t == 0) ? 0 : ls[t - 1];
    for (int k = 0; k < C; ++k) {
        const int idx = start + k;
        if (idx < NODES) { off[idx] = base; cursor[idx] = base; base += deg[idx]; }
    }
    if (t == 1023) off[NODES] = EDGES;
}

__global__ void place_kernel(const int* __restrict__ dst, int* __restrict__ cursor,
                             int* __restrict__ elist)
{
    const int i = blockIdx.x * blockDim.x + threadIdx.x;
    if (i < EDGES) {
        const int p = atomicAdd(&cursor[dst[i]], 1);
        elist[p] = i;
    }
}

// ---------------------------------------------------------------------------
// Edge MLP (MFMA): e_out = e_in + MLP(concat[e_in, n[src], n[dst]])
// ---------------------------------------------------------------------------
__global__ __launch_bounds__(256)
void edge_mlp(const float* e_in, const float* __restrict__ nf,
              const int* __restrict__ src, const int* __restrict__ dst,
              const unsigned short* __restrict__ Wp1,
              const float* __restrict__ b1, const float* __restrict__ g1,
              const float* __restrict__ be1,
              const unsigned short* __restrict__ Wp2,
              const float* __restrict__ b2, float* e_out)
{
    __shared__ unsigned short Ae[64][392];   // 384 + 8 pad
    __shared__ unsigned short Sl[64][136];   // 128 + 8 pad
    __shared__ float red[4][32][2];
    __shared__ int gidx[2][64];
    const int tid = threadIdx.x;
    const long base = (long)blockIdx.x * 64;

    if (tid < 64)       gidx[0][tid]      = src[base + tid];
    else if (tid < 128) gidx[1][tid - 64] = dst[base + tid - 64];
    __syncthreads();

    #pragma unroll
    for (int it = 0; it < 24; ++it) {
        const int i = tid + it*256;          // 6144 float4 total
        const int row = i / 96;
        const int c = (i - row*96) * 4;
        const float* p;
        if (c < 128)      p = &e_in[(base + row)*DD + c];
        else if (c < 256) p = &nf[(long)gidx[0][row]*DD + (c - 128)];
        else              p = &nf[(long)gidx[1][row]*DD + (c - 256)];
        const float4 v = *(const float4*)p;
        ushort4 o; o.x = f2bf(v.x); o.y = f2bf(v.y); o.z = f2bf(v.z); o.w = f2bf(v.w);
        *(ushort4*)&Ae[row][c] = o;
    }
    __syncthreads();

    const int lane = tid & 63, w = tid >> 6;
    const int wr = w >> 1, wc = w & 1;
    const int R0 = wr*32, C0 = wc*64;
    const int lg = lane >> 4, ll = lane & 15;

    float b1v[4], g1v[4], be1v[4], b2v[4];
    #pragma unroll
    for (int ct = 0; ct < 4; ++ct) {
        const int c = C0 + ct*16 + ll;
        b1v[ct] = b1[c]; g1v[ct] = g1[c]; be1v[ct] = be1[c]; b2v[ct] = b2[c];
    }

    f32x4 acc[2][4] = {};
    #pragma unroll
    for (int kt = 0; kt < 12; ++kt) {
        const v8bf a0 = *(const v8bf*)&Ae[R0 + ll][kt*32 + lg*8];
        const v8bf a1 = *(const v8bf*)&Ae[R0 + 16 + ll][kt*32 + lg*8];
        #pragma unroll
        for (int ct = 0; ct < 4; ++ct) {
            const v8bf b = *(const v8bf*)&Wp1[((kt*8 + wc*4 + ct)*64 + lane)*8];
            acc[0][ct] = __builtin_amdgcn_mfma_f32_16x16x32_bf16(a0, b, acc[0][ct], 0, 0, 0);
            acc[1][ct] = __builtin_amdgcn_mfma_f32_16x16x32_bf16(a1, b, acc[1][ct], 0, 0, 0);
        }
    }

    f32x4 s[2], q[2];
    #pragma unroll
    for (int rt = 0; rt < 2; ++rt) {
        #pragma unroll
        for (int ct = 0; ct < 4; ++ct) acc[rt][ct] += b1v[ct];
        s[rt] = acc[rt][0] + acc[rt][1] + acc[rt][2] + acc[rt][3];
        q[rt] = acc[rt][0]*acc[rt][0] + acc[rt][1]*acc[rt][1]
              + acc[rt][2]*acc[rt][2] + acc[rt][3]*acc[rt][3];
    }
    #pragma unroll
    for (int off = 1; off <= 8; off <<= 1) {
        #pragma unroll
        for (int rt = 0; rt < 2; ++rt) {
            #pragma unroll
            for (int j = 0; j < 4; ++j) {
                s[rt][j] += __shfl_xor(s[rt][j], off);
                q[rt][j] += __shfl_xor(q[rt][j], off);
            }
        }
    }
    if (ll == 0) {
        #pragma unroll
        for (int rt = 0; rt < 2; ++rt)
            #pragma unroll
            for (int j = 0; j < 4; ++j) {
                red[w][rt*16 + lg*4 + j][0] = s[rt][j];
                red[w][rt*16 + lg*4 + j][1] = q[rt][j];
            }
    }
    __syncthreads();

    #pragma unroll
    for (int rt = 0; rt < 2; ++rt) {
        #pragma unroll
        for (int j = 0; j < 4; ++j) {
            const int lr = rt*16 + lg*4 + j;
            const float S = red[2*wr][lr][0] + red[2*wr + 1][lr][0];
            const float Q = red[2*wr][lr][1] + red[2*wr + 1][lr][1];
            const float mu = S * (1.0f/DD);
            const float var = Q * (1.0f/DD) - mu*mu;
            const float inv = rsqrtf(var + 1e-5f);
            #pragma unroll
            for (int ct = 0; ct < 4; ++ct) {
                const float hn = (acc[rt][ct][j] - mu) * inv * g1v[ct] + be1v[ct];
                const float sv = hn / (1.0f + __expf(-hn));
                Sl[R0 + lr][C0 + ct*16 + ll] = f2bf(sv);
            }
        }
    }
    __syncthreads();

    f32x4 acc2[2][4] = {};
    #pragma unroll
    for (int kt = 0; kt < 4; ++kt) {
        const v8bf a0 = *(const v8bf*)&Sl[R0 + ll][kt*32 + lg*8];
        const v8bf a1 = *(const v8bf*)&Sl[R0 + 16 + ll][kt*32 + lg*8];
        #pragma unroll
        for (int ct = 0; ct < 4; ++ct) {
            const v8bf b = *(const v8bf*)&Wp2[((kt*8 + wc*4 + ct)*64 + lane)*8];
            acc2[0][ct] = __builtin_amdgcn_mfma_f32_16x16x32_bf16(a0, b, acc2[0][ct], 0, 0, 0);
            acc2[1][ct] = __builtin_amdgcn_mfma_f32_16x16x32_bf16(a1, b, acc2[1][ct], 0, 0, 0);
        }
    }

    #pragma unroll
    for (int rt = 0; rt < 2; ++rt)
        #pragma unroll
        for (int ct = 0; ct < 4; ++ct)
            #pragma unroll
            for (int j = 0; j < 4; ++j) {
                const long grow = base + R0 + rt*16 + lg*4 + j;
                const int ccol = C0 + ct*16 + ll;
                e_out[grow*DD + ccol] = e_in[grow*DD + ccol] + acc2[rt][ct][j] + b2v[ct];
            }
}

// ---------------------------------------------------------------------------
// Node MLP (MFMA) with fused CSR gather-aggregate:
// n_out = n_in + MLP(concat[n_in, sum_{e: dst[e]=v} e_out[e]])
// ---------------------------------------------------------------------------
__global__ __launch_bounds__(256)
void node_mlp(const float* n_in, const float* __restrict__ e_buf,
              const int* __restrict__ off, const int* __restrict__ elist,
              const unsigned short* __restrict__ Wp1,
              const float* __restrict__ b1, const float* __restrict__ g1,
              const float* __restrict__ be1,
              const unsigned short* __restrict__ Wp2,
              const float* __restrict__ b2, float* n_out)
{
    __shared__ unsigned short Ae[64][264];   // 256 + 8 pad
    __shared__ unsigned short Sl[64][136];
    __shared__ float red[4][32][2];
    const int tid = threadIdx.x;
    const long base = (long)blockIdx.x * 64;

    // stage n_in (cols 0..127)
    #pragma unroll
    for (int it = 0; it < 8; ++it) {
        const int i = tid + it*256;          // 2048 float4
        const int row = i >> 5;
        const int c = (i & 31) * 4;
        float4 v = {0.f, 0.f, 0.f, 0.f};
        if (base + row < NODES) v = *(const float4*)&n_in[(base + row)*DD + c];
        ushort4 o; o.x = f2bf(v.x); o.y = f2bf(v.y); o.z = f2bf(v.z); o.w = f2bf(v.w);
        *(ushort4*)&Ae[row][c] = o;
    }

    // gather-aggregate edges (cols 128..255): 4 threads per row, 32 cols each
    {
        const int r  = tid >> 2;
        const int cs = (tid & 3) * 32;
        const long row = base + r;
        float a[32];
        #pragma unroll
        for (int q = 0; q < 32; ++q) a[q] = 0.f;
        if (row < NODES) {
            const int jb = off[row], je = off[row + 1];
            for (int j = jb; j < je; ++j) {
                const float* p = &e_buf[(long)elist[j]*DD + cs];
                #pragma unroll
                for (int q = 0; q < 8; ++q) {
                    const float4 v = *(const float4*)(p + q*4);
                    a[q*4+0] += v.x; a[q*4+1] += v.y;
                    a[q*4+2] += v.z; a[q*4+3] += v.w;
                }
            }
        }
        #pragma unroll
        for (int q = 0; q < 8; ++q) {
            ushort4 o;
            o.x = f2bf(a[q*4+0]); o.y = f2bf(a[q*4+1]);
            o.z = f2bf(a[q*4+2]); o.w = f2bf(a[q*4+3]);
            *(ushort4*)&Ae[r][DD + cs + q*4] = o;
        }
    }
    __syncthreads();

    const int lane = tid & 63, w = tid >> 6;
    const int wr = w >> 1, wc = w & 1;
    const int R0 = wr*32, C0 = wc*64;
    const int lg = lane >> 4, ll = lane & 15;

    float b1v[4], g1v[4], be1v[4], b2v[4];
    #pragma unroll
    for (int ct = 0; ct < 4; ++ct) {
        const int c = C0 + ct*16 + ll;
        b1v[ct] = b1[c]; g1v[ct] = g1[c]; be1v[ct] = be1[c]; b2v[ct] = b2[c];
    }

    f32x4 acc[2][4] = {};
    #pragma unroll
    for (int kt = 0; kt < 8; ++kt) {
        const v8bf a0 = *(const v8bf*)&Ae[R0 + ll][kt*32 + lg*8];
        const v8bf a1 = *(const v8bf*)&Ae[R0 + 16 + ll][kt*32 + lg*8];
        #pragma unroll
        for (int ct = 0; ct < 4; ++ct) {
            const v8bf b = *(const v8bf*)&Wp1[((kt*8 + wc*4 + ct)*64 + lane)*8];
            acc[0][ct] = __builtin_amdgcn_mfma_f32_16x16x32_bf16(a0, b, acc[0][ct], 0, 0, 0);
            acc[1][ct] = __builtin_amdgcn_mfma_f32_16x16x32_bf16(a1, b, acc[1][ct], 0, 0, 0);
        }
    }

    f32x4 s[2], q[2];
    #pragma unroll
    for (int rt = 0; rt < 2; ++rt) {
        #pragma unroll
        for (int ct = 0; ct < 4; ++ct) acc[rt][ct] += b1v[ct];
        s[rt] = acc[rt][0] + acc[rt][1] + acc[rt][2] + acc[rt][3];
        q[rt] = acc[rt][0]*acc[rt][0] + acc[rt][1]*acc[rt][1]
              + acc[rt][2]*acc[rt][2] + acc[rt][3]*acc[rt][3];
    }
    #pragma unroll
    for (int off_ = 1; off_ <= 8; off_ <<= 1) {
        #pragma unroll
        for (int rt = 0; rt < 2; ++rt) {
            #pragma unroll
            for (int j = 0; j < 4; ++j) {
                s[rt][j] += __shfl_xor(s[rt][j], off_);
                q[rt][j] += __shfl_xor(q[rt][j], off_);
            }
        }
    }
    if (ll == 0) {
        #pragma unroll
        for (int rt = 0; rt < 2; ++rt)
            #pragma unroll
            for (int j = 0; j < 4; ++j) {
                red[w][rt*16 + lg*4 + j][0] = s[rt][j];
                red[w][rt*16 + lg*4 + j][1] = q[rt][j];
            }
    }
    __syncthreads();

    #pragma unroll
    for (int rt = 0; rt < 2; ++rt) {
        #pragma unroll
        for (int j = 0; j < 4; ++j) {
            const int lr = rt*16 + lg*4 + j;
            const float S = red[2*wr][lr][0] + red[2*wr + 1][lr][0];
            const float Q = red[2*wr][lr][1] + red[2*wr + 1][lr][1];
            const float mu = S * (1.0f/DD);
            const float var = Q * (1.0f/DD) - mu*mu;
            const float inv = rsqrtf(var + 1e-5f);
            #pragma unroll
            for (int ct = 0; ct < 4; ++ct) {
                const float hn = (acc[rt][ct][j] - mu) * inv * g1v[ct] + be1v[ct];
                const float sv = hn / (1.0f + __expf(-hn));
                Sl[R0 + lr][C0 + ct*16 + ll] = f2bf(sv);
            }
        }
    }
    __syncthreads();

    f32x4 acc2[2][4] = {};
    #pragma unroll
    for (int kt = 0; kt < 4; ++kt) {
        const v8bf a0 = *(const v8bf*)&Sl[R0 + ll][kt*32 + lg*8];
        const v8bf a1 = *(const v8bf*)&Sl[R0 + 16 + ll][kt*32 + lg*8];
        #pragma unroll
        for (int ct = 0; ct < 4; ++ct) {
            const v8bf b = *(const v8bf*)&Wp2[((kt*8 + wc*4 + ct)*64 + lane)*8];
            acc2[0][ct] = __builtin_amdgcn_mfma_f32_16x16x32_bf16(a0, b, acc2[0][ct], 0, 0, 0);
            acc2[1][ct] = __builtin_amdgcn_mfma_f32_16x16x32_bf16(a1, b, acc2[1][ct], 0, 0, 0);
        }
    }

    #pragma unroll
    for (int rt = 0; rt < 2; ++rt)
        #pragma unroll
        for (int ct = 0; ct < 4; ++ct)
            #pragma unroll
            for (int j = 0; j < 4; ++j) {
                const long grow = base + R0 + rt*16 + lg*4 + j;
                if (grow < NODES) {
                    const int ccol = C0 + ct*16 + ll;
                    n_out[grow*DD + ccol] = n_in[grow*DD + ccol] + acc2[rt][ct][j] + b2v[ct];
                }
            }
}

extern "C" void kernel_launch(void* const* d_in, const int* in_sizes, int n_in,
                              void* d_out, int out_size, void* d_ws, size_t ws_size,
                              hipStream_t stream) {
    const float* node_feat = (const float*)d_in[0];
    const float* edge_attr = (const float*)d_in[1];
    const int*   edge_index= (const int*)d_in[2];
    const float* eW1 = (const float*)d_in[3];
    const float* eb1 = (const float*)d_in[4];
    const float* eg1 = (const float*)d_in[5];
    const float* ebe1= (const float*)d_in[6];
    const float* eW2 = (const float*)d_in[7];
    const float* eb2 = (const float*)d_in[8];
    const float* nW1 = (const float*)d_in[9];
    const float* nb1 = (const float*)d_in[10];
    const float* ng1 = (const float*)d_in[11];
    const float* nbe1= (const float*)d_in[12];
    const float* nW2 = (const float*)d_in[13];
    const float* nb2 = (const float*)d_in[14];

    const int N = NODES, E = EDGES;
    const int* src  = edge_index;
    const int* dstI = edge_index + E;

    float* out_n = (float*)d_out;
    float* out_e = (float*)d_out + (size_t)N * DD;

    // ws layout: [wp: 229376 ushorts = 458752 B][deg:50000][off:50001][cursor:50000][elist:256000]
    unsigned short* wp = (unsigned short*)d_ws;
    int* ib     = (int*)((char*)d_ws + 458752);
    int* deg    = ib;
    int* off    = ib + 50000;
    int* cursor = ib + 100001;
    int* elist  = ib + 150001;

    pack_weights<<<56, 512, 0, stream>>>(eW1, eW2, nW1, nW2, wp);

    // CSR build (dst is the same for both layers)
    hipMemsetAsync(deg, 0, (size_t)N * sizeof(int), stream);
    hist_kernel<<<(E + 255)/256, 256, 0, stream>>>(dstI, deg);
    scan_deg<<<1, 1024, 0, stream>>>(deg, off, cursor);
    place_kernel<<<(E + 255)/256, 256, 0, stream>>>(dstI, cursor, elist);

    for (int l = 0; l < 2; ++l) {
        const unsigned short* eWp1 = wp + l*49152;
        const unsigned short* eWp2 = wp + 98304 + l*16384;
        const unsigned short* nWp1 = wp + 131072 + l*32768;
        const unsigned short* nWp2 = wp + 196608 + l*16384;
        const float* ein = (l == 0) ? edge_attr : out_e;
        const float* nin = (l == 0) ? node_feat : out_n;

        edge_mlp<<<E/64, 256, 0, stream>>>(ein, nin, src, dstI,
            eWp1, eb1 + l*DD, eg1 + l*DD, ebe1 + l*DD, eWp2, eb2 + l*DD, out_e);
        node_mlp<<<(N + 63)/64, 256, 0, stream>>>(nin, out_e, off, elist,
            nWp1, nb1 + l*DD, ng1 + l*DD, nbe1 + l*DD, nWp2, nb2 + l*DD, out_n);
    }
}

// Round 4
// 547.051 us; speedup vs baseline: 3.9010x; 1.3873x over previous
//
#include <hip/hip_runtime.h>
#include <hip/hip_bf16.h>

typedef float f32x4 __attribute__((ext_vector_type(4)));
typedef __bf16 v8bf __attribute__((ext_vector_type(8)));

#define DD 128
#define EDGES 256000
#define NODES 50000

__device__ __forceinline__ unsigned short f2bf(float f) {
    union { float f; unsigned u; } v; v.f = f;
    unsigned r = v.u + 0x7fffu + ((v.u >> 16) & 1u);
    return (unsigned short)(r >> 16);
}
__device__ __forceinline__ float bf2f(unsigned short u) {
    union { unsigned u; float f; } v; v.u = ((unsigned)u) << 16; return v.f;
}

// ---------------------------------------------------------------------------
// Weight prep: fp32 -> bf16, packed in MFMA B-fragment order.
// dst[((kt*8+ct)*64+l)*8 + j] = bf16(W[(kt*32+(l>>4)*8+j)*128 + ct*16+(l&15)])
// ---------------------------------------------------------------------------
__global__ __launch_bounds__(512)
void pack_weights(const float* __restrict__ eW1, const float* __restrict__ eW2,
                  const float* __restrict__ nW1, const float* __restrict__ nW2,
                  unsigned short* __restrict__ wp)
{
    const int b = blockIdx.x;            // 0..55
    const int layer = b / 28;
    const int u = b % 28;
    const float* W; int kt; unsigned short* dst;
    if (u < 12)      { W = eW1 + layer*384*128; kt = u;      dst = wp + layer*49152; }
    else if (u < 16) { W = eW2 + layer*128*128; kt = u - 12; dst = wp + 98304 + layer*16384; }
    else if (u < 24) { W = nW1 + layer*256*128; kt = u - 16; dst = wp + 131072 + layer*32768; }
    else             { W = nW2 + layer*128*128; kt = u - 24; dst = wp + 196608 + layer*16384; }
    const int t = threadIdx.x;           // 512 = 8 ct * 64 lanes
    const int ct = t >> 6, l = t & 63;
    #pragma unroll
    for (int j = 0; j < 8; ++j) {
        const int k = kt*32 + ((l >> 4) * 8) + j;
        const int c = ct*16 + (l & 15);
        dst[((kt*8 + ct)*64 + l)*8 + j] = f2bf(W[k*128 + c]);
    }
}

// ---------------------------------------------------------------------------
// CSR build: histogram -> scan -> placement (dst is layer-invariant)
// ---------------------------------------------------------------------------
__global__ void hist_kernel(const int* __restrict__ dst, int* __restrict__ deg)
{
    const int i = blockIdx.x * blockDim.x + threadIdx.x;
    if (i < EDGES) atomicAdd(&deg[dst[i]], 1);
}

__global__ __launch_bounds__(1024)
void scan_deg(const int* __restrict__ deg, int* __restrict__ off,
              int* __restrict__ cursor)
{
    __shared__ int ls[1024];
    const int t = threadIdx.x;
    const int C = 49;                    // 1024*49 >= 50000
    const int start = t * C;
    int s = 0;
    for (int k = 0; k < C; ++k) {
        const int idx = start + k;
        if (idx < NODES) s += deg[idx];
    }
    ls[t] = s;
    __syncthreads();
    for (int d = 1; d < 1024; d <<= 1) {
        int v = 0;
        if (t >= d) v = ls[t - d];
        __syncthreads();
        if (t >= d) ls[t] += v;
        __syncthreads();
    }
    int base = (t == 0) ? 0 : ls[t - 1];
    for (int k = 0; k < C; ++k) {
        const int idx = start + k;
        if (idx < NODES) { off[idx] = base; cursor[idx] = base; base += deg[idx]; }
    }
    if (t == 1023) off[NODES] = EDGES;
}

__global__ void place_kernel(const int* __restrict__ dst, int* __restrict__ cursor,
                             int* __restrict__ elist)
{
    const int i = blockIdx.x * blockDim.x + threadIdx.x;
    if (i < EDGES) {
        const int p = atomicAdd(&cursor[dst[i]], 1);
        elist[p] = i;
    }
}

// ---------------------------------------------------------------------------
// Edge MLP (MFMA): e_out = bf16(e_in) + MLP(concat[e_in, n[src], n[dst]])
// Residual comes from the staged LDS tile (no global re-read).
// LDS: AeE 17408 + AeG 33792 (Sl overlays AeG) + red 1024 + gidx 512 = 52.7KB
//   -> 3 blocks/CU.
// ---------------------------------------------------------------------------
__global__ __launch_bounds__(256)
void edge_mlp(const float* e_in, const float* __restrict__ nf,
              const int* __restrict__ src, const int* __restrict__ dst,
              const unsigned short* __restrict__ Wp1,
              const float* __restrict__ b1, const float* __restrict__ g1,
              const float* __restrict__ be1,
              const unsigned short* __restrict__ Wp2,
              const float* __restrict__ b2, float* e_out)
{
    __shared__ __align__(16) unsigned short AeE[64][136];   // e cols 0-127
    __shared__ __align__(16) unsigned short AeG[64][264];   // src|dst gathers
    __shared__ float red[4][32][2];
    __shared__ int gidx[128];
    unsigned short (*Sl)[136] = reinterpret_cast<unsigned short(*)[136]>(&AeG[0][0]);

    const int tid = threadIdx.x;
    const long base = (long)blockIdx.x * 64;

    if (tid < 128) gidx[tid] = (tid < 64) ? src[base + tid] : dst[base + (tid - 64)];

    const int lane = tid & 63, w = tid >> 6;
    const int wr = w >> 1, wc = w & 1;
    const int R0 = wr*32, C0 = wc*64;
    const int lg = lane >> 4, ll = lane & 15;

    float b1v[4], g1v[4], be1v[4], b2v[4];
    #pragma unroll
    for (int ct = 0; ct < 4; ++ct) {
        const int c = C0 + ct*16 + ll;
        b1v[ct] = b1[c]; g1v[ct] = g1[c]; be1v[ct] = be1[c]; b2v[ct] = b2[c];
    }

    // stage e tile: 64 rows x 32 float4
    #pragma unroll
    for (int it = 0; it < 8; ++it) {
        const int i = tid + it*256;
        const int row = i >> 5;
        const int c = (i & 31) * 4;
        const float4 v = *(const float4*)&e_in[(base + row)*DD + c];
        ushort4 o; o.x = f2bf(v.x); o.y = f2bf(v.y); o.z = f2bf(v.z); o.w = f2bf(v.w);
        *(ushort4*)&AeE[row][c] = o;
    }
    __syncthreads();   // gidx ready

    // gather tiles: 128 gathered rows x 32 float4
    #pragma unroll
    for (int it = 0; it < 16; ++it) {
        const int i = tid + it*256;
        const int gr = i >> 5;            // 0..127
        const int c = (i & 31) * 4;
        const float4 v = *(const float4*)&nf[(long)gidx[gr]*DD + c];
        ushort4 o; o.x = f2bf(v.x); o.y = f2bf(v.y); o.z = f2bf(v.z); o.w = f2bf(v.w);
        *(ushort4*)&AeG[gr & 63][(gr >> 6)*128 + c] = o;
    }
    __syncthreads();

    // GEMM1: [64x384] @ [384x128]
    f32x4 acc[2][4] = {};
    #pragma unroll
    for (int kt = 0; kt < 12; ++kt) {
        const unsigned short* a0p = (kt < 4) ? &AeE[R0 + ll][kt*32 + lg*8]
                                             : &AeG[R0 + ll][(kt-4)*32 + lg*8];
        const unsigned short* a1p = (kt < 4) ? &AeE[R0 + 16 + ll][kt*32 + lg*8]
                                             : &AeG[R0 + 16 + ll][(kt-4)*32 + lg*8];
        const v8bf a0 = *(const v8bf*)a0p;
        const v8bf a1 = *(const v8bf*)a1p;
        #pragma unroll
        for (int ct = 0; ct < 4; ++ct) {
            const v8bf b = *(const v8bf*)&Wp1[((kt*8 + wc*4 + ct)*64 + lane)*8];
            acc[0][ct] = __builtin_amdgcn_mfma_f32_16x16x32_bf16(a0, b, acc[0][ct], 0, 0, 0);
            acc[1][ct] = __builtin_amdgcn_mfma_f32_16x16x32_bf16(a1, b, acc[1][ct], 0, 0, 0);
        }
    }

    // bias + LN stats
    f32x4 s[2], q[2];
    #pragma unroll
    for (int rt = 0; rt < 2; ++rt) {
        #pragma unroll
        for (int ct = 0; ct < 4; ++ct) acc[rt][ct] += b1v[ct];
        s[rt] = acc[rt][0] + acc[rt][1] + acc[rt][2] + acc[rt][3];
        q[rt] = acc[rt][0]*acc[rt][0] + acc[rt][1]*acc[rt][1]
              + acc[rt][2]*acc[rt][2] + acc[rt][3]*acc[rt][3];
    }
    #pragma unroll
    for (int off = 1; off <= 8; off <<= 1) {
        #pragma unroll
        for (int rt = 0; rt < 2; ++rt)
            #pragma unroll
            for (int j = 0; j < 4; ++j) {
                s[rt][j] += __shfl_xor(s[rt][j], off);
                q[rt][j] += __shfl_xor(q[rt][j], off);
            }
    }
    if (ll == 0) {
        #pragma unroll
        for (int rt = 0; rt < 2; ++rt)
            #pragma unroll
            for (int j = 0; j < 4; ++j) {
                red[w][rt*16 + lg*4 + j][0] = s[rt][j];
                red[w][rt*16 + lg*4 + j][1] = q[rt][j];
            }
    }
    __syncthreads();   // also: all waves done reading AeG -> Sl overlay safe

    // LN + SiLU -> Sl (overlays AeG)
    #pragma unroll
    for (int rt = 0; rt < 2; ++rt) {
        #pragma unroll
        for (int j = 0; j < 4; ++j) {
            const int lr = rt*16 + lg*4 + j;
            const float S = red[2*wr][lr][0] + red[2*wr + 1][lr][0];
            const float Q = red[2*wr][lr][1] + red[2*wr + 1][lr][1];
            const float mu = S * (1.0f/DD);
            const float var = Q * (1.0f/DD) - mu*mu;
            const float inv = rsqrtf(var + 1e-5f);
            #pragma unroll
            for (int ct = 0; ct < 4; ++ct) {
                const float hn = (acc[rt][ct][j] - mu) * inv * g1v[ct] + be1v[ct];
                const float sv = hn / (1.0f + __expf(-hn));
                Sl[R0 + lr][C0 + ct*16 + ll] = f2bf(sv);
            }
        }
    }
    __syncthreads();

    // GEMM2: [64x128] @ [128x128]
    f32x4 acc2[2][4] = {};
    #pragma unroll
    for (int kt = 0; kt < 4; ++kt) {
        const v8bf a0 = *(const v8bf*)&Sl[R0 + ll][kt*32 + lg*8];
        const v8bf a1 = *(const v8bf*)&Sl[R0 + 16 + ll][kt*32 + lg*8];
        #pragma unroll
        for (int ct = 0; ct < 4; ++ct) {
            const v8bf b = *(const v8bf*)&Wp2[((kt*8 + wc*4 + ct)*64 + lane)*8];
            acc2[0][ct] = __builtin_amdgcn_mfma_f32_16x16x32_bf16(a0, b, acc2[0][ct], 0, 0, 0);
            acc2[1][ct] = __builtin_amdgcn_mfma_f32_16x16x32_bf16(a1, b, acc2[1][ct], 0, 0, 0);
        }
    }

    // residual from LDS tile + store
    #pragma unroll
    for (int rt = 0; rt < 2; ++rt)
        #pragma unroll
        for (int ct = 0; ct < 4; ++ct)
            #pragma unroll
            for (int j = 0; j < 4; ++j) {
                const int lr = rt*16 + lg*4 + j;
                const int col = C0 + ct*16 + ll;
                const float res = bf2f(AeE[R0 + lr][col]);
                e_out[(base + R0 + lr)*DD + col] = res + acc2[rt][ct][j] + b2v[ct];
            }
}

// ---------------------------------------------------------------------------
// Node MLP (MFMA) with fused CSR gather-aggregate.
// LDS: AnN 17408 + AnG 17408 (Sl overlays AnG) + red 1024 = 35.8KB -> 4 blk/CU
// ---------------------------------------------------------------------------
__global__ __launch_bounds__(256)
void node_mlp(const float* n_in, const float* __restrict__ e_buf,
              const int* __restrict__ off, const int* __restrict__ elist,
              const unsigned short* __restrict__ Wp1,
              const float* __restrict__ b1, const float* __restrict__ g1,
              const float* __restrict__ be1,
              const unsigned short* __restrict__ Wp2,
              const float* __restrict__ b2, float* n_out)
{
    __shared__ __align__(16) unsigned short AnN[64][136];
    __shared__ __align__(16) unsigned short AnG[64][136];
    __shared__ float red[4][32][2];
    unsigned short (*Sl)[136] = reinterpret_cast<unsigned short(*)[136]>(&AnG[0][0]);

    const int tid = threadIdx.x;
    const long base = (long)blockIdx.x * 64;

    const int lane = tid & 63, w = tid >> 6;
    const int wr = w >> 1, wc = w & 1;
    const int R0 = wr*32, C0 = wc*64;
    const int lg = lane >> 4, ll = lane & 15;

    float b1v[4], g1v[4], be1v[4], b2v[4];
    #pragma unroll
    for (int ct = 0; ct < 4; ++ct) {
        const int c = C0 + ct*16 + ll;
        b1v[ct] = b1[c]; g1v[ct] = g1[c]; be1v[ct] = be1[c]; b2v[ct] = b2[c];
    }

    // gather-aggregate: 4 threads/row x 32 cols
    {
        const int r  = tid >> 2;
        const int cq = (tid & 3) * 32;
        const long row = base + r;
        float a[32];
        #pragma unroll
        for (int q = 0; q < 32; ++q) a[q] = 0.f;
        if (row < NODES) {
            const int jb = off[row], je = off[row + 1];
            for (int j = jb; j < je; ++j) {
                const float* p = &e_buf[(long)elist[j]*DD + cq];
                #pragma unroll
                for (int q = 0; q < 8; ++q) {
                    const float4 v = *(const float4*)(p + q*4);
                    a[q*4+0] += v.x; a[q*4+1] += v.y;
                    a[q*4+2] += v.z; a[q*4+3] += v.w;
                }
            }
        }
        #pragma unroll
        for (int q = 0; q < 8; ++q) {
            ushort4 o;
            o.x = f2bf(a[q*4+0]); o.y = f2bf(a[q*4+1]);
            o.z = f2bf(a[q*4+2]); o.w = f2bf(a[q*4+3]);
            *(ushort4*)&AnG[r][cq + q*4] = o;
        }
    }

    // stage n tile
    #pragma unroll
    for (int it = 0; it < 8; ++it) {
        const int i = tid + it*256;
        const int row = i >> 5;
        const int c = (i & 31) * 4;
        float4 v = {0.f, 0.f, 0.f, 0.f};
        if (base + row < NODES) v = *(const float4*)&n_in[(base + row)*DD + c];
        ushort4 o; o.x = f2bf(v.x); o.y = f2bf(v.y); o.z = f2bf(v.z); o.w = f2bf(v.w);
        *(ushort4*)&AnN[row][c] = o;
    }
    __syncthreads();

    // GEMM1: [64x256] @ [256x128]
    f32x4 acc[2][4] = {};
    #pragma unroll
    for (int kt = 0; kt < 8; ++kt) {
        const unsigned short* a0p = (kt < 4) ? &AnN[R0 + ll][kt*32 + lg*8]
                                             : &AnG[R0 + ll][(kt-4)*32 + lg*8];
        const unsigned short* a1p = (kt < 4) ? &AnN[R0 + 16 + ll][kt*32 + lg*8]
                                             : &AnG[R0 + 16 + ll][(kt-4)*32 + lg*8];
        const v8bf a0 = *(const v8bf*)a0p;
        const v8bf a1 = *(const v8bf*)a1p;
        #pragma unroll
        for (int ct = 0; ct < 4; ++ct) {
            const v8bf b = *(const v8bf*)&Wp1[((kt*8 + wc*4 + ct)*64 + lane)*8];
            acc[0][ct] = __builtin_amdgcn_mfma_f32_16x16x32_bf16(a0, b, acc[0][ct], 0, 0, 0);
            acc[1][ct] = __builtin_amdgcn_mfma_f32_16x16x32_bf16(a1, b, acc[1][ct], 0, 0, 0);
        }
    }

    f32x4 s[2], q[2];
    #pragma unroll
    for (int rt = 0; rt < 2; ++rt) {
        #pragma unroll
        for (int ct = 0; ct < 4; ++ct) acc[rt][ct] += b1v[ct];
        s[rt] = acc[rt][0] + acc[rt][1] + acc[rt][2] + acc[rt][3];
        q[rt] = acc[rt][0]*acc[rt][0] + acc[rt][1]*acc[rt][1]
              + acc[rt][2]*acc[rt][2] + acc[rt][3]*acc[rt][3];
    }
    #pragma unroll
    for (int off_ = 1; off_ <= 8; off_ <<= 1) {
        #pragma unroll
        for (int rt = 0; rt < 2; ++rt)
            #pragma unroll
            for (int j = 0; j < 4; ++j) {
                s[rt][j] += __shfl_xor(s[rt][j], off_);
                q[rt][j] += __shfl_xor(q[rt][j], off_);
            }
    }
    if (ll == 0) {
        #pragma unroll
        for (int rt = 0; rt < 2; ++rt)
            #pragma unroll
            for (int j = 0; j < 4; ++j) {
                red[w][rt*16 + lg*4 + j][0] = s[rt][j];
                red[w][rt*16 + lg*4 + j][1] = q[rt][j];
            }
    }
    __syncthreads();

    #pragma unroll
    for (int rt = 0; rt < 2; ++rt) {
        #pragma unroll
        for (int j = 0; j < 4; ++j) {
            const int lr = rt*16 + lg*4 + j;
            const float S = red[2*wr][lr][0] + red[2*wr + 1][lr][0];
            const float Q = red[2*wr][lr][1] + red[2*wr + 1][lr][1];
            const float mu = S * (1.0f/DD);
            const float var = Q * (1.0f/DD) - mu*mu;
            const float inv = rsqrtf(var + 1e-5f);
            #pragma unroll
            for (int ct = 0; ct < 4; ++ct) {
                const float hn = (acc[rt][ct][j] - mu) * inv * g1v[ct] + be1v[ct];
                const float sv = hn / (1.0f + __expf(-hn));
                Sl[R0 + lr][C0 + ct*16 + ll] = f2bf(sv);
            }
        }
    }
    __syncthreads();

    f32x4 acc2[2][4] = {};
    #pragma unroll
    for (int kt = 0; kt < 4; ++kt) {
        const v8bf a0 = *(const v8bf*)&Sl[R0 + ll][kt*32 + lg*8];
        const v8bf a1 = *(const v8bf*)&Sl[R0 + 16 + ll][kt*32 + lg*8];
        #pragma unroll
        for (int ct = 0; ct < 4; ++ct) {
            const v8bf b = *(const v8bf*)&Wp2[((kt*8 + wc*4 + ct)*64 + lane)*8];
            acc2[0][ct] = __builtin_amdgcn_mfma_f32_16x16x32_bf16(a0, b, acc2[0][ct], 0, 0, 0);
            acc2[1][ct] = __builtin_amdgcn_mfma_f32_16x16x32_bf16(a1, b, acc2[1][ct], 0, 0, 0);
        }
    }

    // exact fp32 residual (n arrays are small/L2-hot) + store
    #pragma unroll
    for (int rt = 0; rt < 2; ++rt)
        #pragma unroll
        for (int ct = 0; ct < 4; ++ct)
            #pragma unroll
            for (int j = 0; j < 4; ++j) {
                const long grow = base + R0 + rt*16 + lg*4 + j;
                if (grow < NODES) {
                    const int col = C0 + ct*16 + ll;
                    n_out[grow*DD + col] = n_in[grow*DD + col] + acc2[rt][ct][j] + b2v[ct];
                }
            }
}

extern "C" void kernel_launch(void* const* d_in, const int* in_sizes, int n_in,
                              void* d_out, int out_size, void* d_ws, size_t ws_size,
                              hipStream_t stream) {
    const float* node_feat = (const float*)d_in[0];
    const float* edge_attr = (const float*)d_in[1];
    const int*   edge_index= (const int*)d_in[2];
    const float* eW1 = (const float*)d_in[3];
    const float* eb1 = (const float*)d_in[4];
    const float* eg1 = (const float*)d_in[5];
    const float* ebe1= (const float*)d_in[6];
    const float* eW2 = (const float*)d_in[7];
    const float* eb2 = (const float*)d_in[8];
    const float* nW1 = (const float*)d_in[9];
    const float* nb1 = (const float*)d_in[10];
    const float* ng1 = (const float*)d_in[11];
    const float* nbe1= (const float*)d_in[12];
    const float* nW2 = (const float*)d_in[13];
    const float* nb2 = (const float*)d_in[14];

    const int N = NODES, E = EDGES;
    const int* src  = edge_index;
    const int* dstI = edge_index + E;

    float* out_n = (float*)d_out;
    float* out_e = (float*)d_out + (size_t)N * DD;

    // ws: [wp: 229376 ushorts][deg:50000][off:50001][cursor:50000][elist:256000]
    unsigned short* wp = (unsigned short*)d_ws;
    int* ib     = (int*)((char*)d_ws + 458752);
    int* deg    = ib;
    int* off    = ib + 50000;
    int* cursor = ib + 100001;
    int* elist  = ib + 150001;

    pack_weights<<<56, 512, 0, stream>>>(eW1, eW2, nW1, nW2, wp);

    hipMemsetAsync(deg, 0, (size_t)N * sizeof(int), stream);
    hist_kernel<<<(E + 255)/256, 256, 0, stream>>>(dstI, deg);
    scan_deg<<<1, 1024, 0, stream>>>(deg, off, cursor);
    place_kernel<<<(E + 255)/256, 256, 0, stream>>>(dstI, cursor, elist);

    for (int l = 0; l < 2; ++l) {
        const unsigned short* eWp1 = wp + l*49152;
        const unsigned short* eWp2 = wp + 98304 + l*16384;
        const unsigned short* nWp1 = wp + 131072 + l*32768;
        const unsigned short* nWp2 = wp + 196608 + l*16384;
        const float* ein = (l == 0) ? edge_attr : out_e;
        const float* nin = (l == 0) ? node_feat : out_n;

        edge_mlp<<<E/64, 256, 0, stream>>>(ein, nin, src, dstI,
            eWp1, eb1 + l*DD, eg1 + l*DD, ebe1 + l*DD, eWp2, eb2 + l*DD, out_e);
        node_mlp<<<(N + 63)/64, 256, 0, stream>>>(nin, out_e, off, elist,
            nWp1, nb1 + l*DD, ng1 + l*DD, nbe1 + l*DD, nWp2, nb2 + l*DD, out_n);
    }
}

// Round 5
// 509.838 us; speedup vs baseline: 4.1857x; 1.0730x over previous
//
#include <hip/hip_runtime.h>
#include <hip/hip_bf16.h>

typedef float f32x4 __attribute__((ext_vector_type(4)));
typedef __bf16 v8bf __attribute__((ext_vector_type(8)));

#define DD 128
#define EDGES 256000
#define NODES 50000

__device__ __forceinline__ unsigned short f2bf(float f) {
    union { float f; unsigned u; } v; v.f = f;
    unsigned r = v.u + 0x7fffu + ((v.u >> 16) & 1u);
    return (unsigned short)(r >> 16);
}
__device__ __forceinline__ float bf2f(unsigned short u) {
    union { unsigned u; float f; } v; v.u = ((unsigned)u) << 16; return v.f;
}

// ---------------------------------------------------------------------------
// Weight prep: fp32 -> bf16, packed in MFMA B-fragment order.
// ---------------------------------------------------------------------------
__global__ __launch_bounds__(512)
void pack_weights(const float* __restrict__ eW1, const float* __restrict__ eW2,
                  const float* __restrict__ nW1, const float* __restrict__ nW2,
                  unsigned short* __restrict__ wp)
{
    const int b = blockIdx.x;            // 0..55
    const int layer = b / 28;
    const int u = b % 28;
    const float* W; int kt; unsigned short* dst;
    if (u < 12)      { W = eW1 + layer*384*128; kt = u;      dst = wp + layer*49152; }
    else if (u < 16) { W = eW2 + layer*128*128; kt = u - 12; dst = wp + 98304 + layer*16384; }
    else if (u < 24) { W = nW1 + layer*256*128; kt = u - 16; dst = wp + 131072 + layer*32768; }
    else             { W = nW2 + layer*128*128; kt = u - 24; dst = wp + 196608 + layer*16384; }
    const int t = threadIdx.x;           // 512 = 8 ct * 64 lanes
    const int ct = t >> 6, l = t & 63;
    #pragma unroll
    for (int j = 0; j < 8; ++j) {
        const int k = kt*32 + ((l >> 4) * 8) + j;
        const int c = ct*16 + (l & 15);
        dst[((kt*8 + ct)*64 + l)*8 + j] = f2bf(W[k*128 + c]);
    }
}

// ---------------------------------------------------------------------------
// CSR build
// ---------------------------------------------------------------------------
__global__ void hist_kernel(const int* __restrict__ dst, int* __restrict__ deg)
{
    const int i = blockIdx.x * blockDim.x + threadIdx.x;
    if (i < EDGES) atomicAdd(&deg[dst[i]], 1);
}

__global__ __launch_bounds__(1024)
void scan_deg(const int* __restrict__ deg, int* __restrict__ off,
              int* __restrict__ cursor)
{
    __shared__ int ls[1024];
    const int t = threadIdx.x;
    const int C = 49;
    const int start = t * C;
    int s = 0;
    for (int k = 0; k < C; ++k) {
        const int idx = start + k;
        if (idx < NODES) s += deg[idx];
    }
    ls[t] = s;
    __syncthreads();
    for (int d = 1; d < 1024; d <<= 1) {
        int v = 0;
        if (t >= d) v = ls[t - d];
        __syncthreads();
        if (t >= d) ls[t] += v;
        __syncthreads();
    }
    int base = (t == 0) ? 0 : ls[t - 1];
    for (int k = 0; k < C; ++k) {
        const int idx = start + k;
        if (idx < NODES) { off[idx] = base; cursor[idx] = base; base += deg[idx]; }
    }
    if (t == 1023) off[NODES] = EDGES;
}

__global__ void place_kernel(const int* __restrict__ dst, int* __restrict__ cursor,
                             int* __restrict__ elist)
{
    const int i = blockIdx.x * blockDim.x + threadIdx.x;
    if (i < EDGES) {
        const int p = atomicAdd(&cursor[dst[i]], 1);
        elist[p] = i;
    }
}

// ---------------------------------------------------------------------------
// Edge MLP (MFMA), templated on input/output dtype (fp32 or bf16-as-ushort).
// LDS: AeE 17408 + AeG 16896 + red 1024 + gidx 512 = 35840 B -> 4 blocks/CU.
// dst-row gathers are prefetched into registers and written to the AeG panel
// after GEMM1's first half (latency hidden under MFMA).
// ---------------------------------------------------------------------------
template <typename TIN, typename TOUT>
__global__ __launch_bounds__(256, 4)
void edge_mlp(const TIN* e_in, const float* __restrict__ nf,
              const int* __restrict__ src, const int* __restrict__ dst,
              const unsigned short* __restrict__ Wp1,
              const float* __restrict__ b1, const float* __restrict__ g1,
              const float* __restrict__ be1,
              const unsigned short* __restrict__ Wp2,
              const float* __restrict__ b2, TOUT* e_out)
{
    __shared__ __align__(16) unsigned short AeE[64][136];   // e cols 0-127
    __shared__ __align__(16) unsigned short AeG[64][132];   // src panel, then dst, then Sl
    __shared__ float red[4][32][2];
    __shared__ int gidx[128];

    const int tid = threadIdx.x;
    const long base = (long)blockIdx.x * 64;

    if (tid < 128) gidx[tid] = (tid < 64) ? src[base + tid] : dst[base + (tid - 64)];

    const int lane = tid & 63, w = tid >> 6;
    const int wr = w >> 1, wc = w & 1;
    const int R0 = wr*32, C0 = wc*64;
    const int lg = lane >> 4, ll = lane & 15;

    // stage e tile
    if constexpr (sizeof(TIN) == 4) {
        #pragma unroll
        for (int it = 0; it < 8; ++it) {
            const int i = tid + it*256;
            const int row = i >> 5;
            const int c = (i & 31) * 4;
            const float4 v = *(const float4*)&e_in[(base + row)*DD + c];
            ushort4 o; o.x = f2bf(v.x); o.y = f2bf(v.y); o.z = f2bf(v.z); o.w = f2bf(v.w);
            *(ushort4*)&AeE[row][c] = o;
        }
    } else {
        #pragma unroll
        for (int it = 0; it < 4; ++it) {
            const int i = tid + it*256;
            const int row = i >> 4;
            const int c = (i & 15) * 8;
            *(uint4*)&AeE[row][c] = *(const uint4*)&e_in[(base + row)*DD + c];
        }
    }
    __syncthreads();   // gidx + AeE ready

    // src gather -> AeG
    #pragma unroll
    for (int it = 0; it < 8; ++it) {
        const int i = tid + it*256;
        const int row = i >> 5;
        const int c = (i & 31) * 4;
        const float4 v = *(const float4*)&nf[(long)gidx[row]*DD + c];
        ushort4 o; o.x = f2bf(v.x); o.y = f2bf(v.y); o.z = f2bf(v.z); o.w = f2bf(v.w);
        *(ushort4*)&AeG[row][c] = o;
    }
    // dst gather -> registers (latency overlapped with GEMM1 first half)
    float4 dreg[8];
    #pragma unroll
    for (int it = 0; it < 8; ++it) {
        const int i = tid + it*256;
        const int row = i >> 5;
        const int c = (i & 31) * 4;
        dreg[it] = *(const float4*)&nf[(long)gidx[64 + row]*DD + c];
    }
    __syncthreads();   // AeG(src) ready

    float b1v[4], g1v[4], be1v[4], b2v[4];
    #pragma unroll
    for (int ct = 0; ct < 4; ++ct) {
        const int c = C0 + ct*16 + ll;
        b1v[ct] = b1[c]; g1v[ct] = g1[c]; be1v[ct] = be1[c]; b2v[ct] = b2[c];
    }

    // GEMM1 first half: kt 0..7 (e cols + src cols)
    f32x4 acc[2][4] = {};
    #pragma unroll
    for (int kt = 0; kt < 8; ++kt) {
        const unsigned short* a0p = (kt < 4) ? &AeE[R0 + ll][kt*32 + lg*8]
                                             : &AeG[R0 + ll][(kt-4)*32 + lg*8];
        const unsigned short* a1p = (kt < 4) ? &AeE[R0 + 16 + ll][kt*32 + lg*8]
                                             : &AeG[R0 + 16 + ll][(kt-4)*32 + lg*8];
        const v8bf a0 = *(const v8bf*)a0p;
        const v8bf a1 = *(const v8bf*)a1p;
        #pragma unroll
        for (int ct = 0; ct < 4; ++ct) {
            const v8bf b = *(const v8bf*)&Wp1[((kt*8 + wc*4 + ct)*64 + lane)*8];
            acc[0][ct] = __builtin_amdgcn_mfma_f32_16x16x32_bf16(a0, b, acc[0][ct], 0, 0, 0);
            acc[1][ct] = __builtin_amdgcn_mfma_f32_16x16x32_bf16(a1, b, acc[1][ct], 0, 0, 0);
        }
    }
    __syncthreads();   // all waves done reading AeG(src)

    // write dst regs -> AeG
    #pragma unroll
    for (int it = 0; it < 8; ++it) {
        const int i = tid + it*256;
        const int row = i >> 5;
        const int c = (i & 31) * 4;
        ushort4 o; o.x = f2bf(dreg[it].x); o.y = f2bf(dreg[it].y);
        o.z = f2bf(dreg[it].z); o.w = f2bf(dreg[it].w);
        *(ushort4*)&AeG[row][c] = o;
    }
    __syncthreads();

    // GEMM1 second half: kt 8..11 (dst cols)
    #pragma unroll
    for (int kt = 8; kt < 12; ++kt) {
        const v8bf a0 = *(const v8bf*)&AeG[R0 + ll][(kt-8)*32 + lg*8];
        const v8bf a1 = *(const v8bf*)&AeG[R0 + 16 + ll][(kt-8)*32 + lg*8];
        #pragma unroll
        for (int ct = 0; ct < 4; ++ct) {
            const v8bf b = *(const v8bf*)&Wp1[((kt*8 + wc*4 + ct)*64 + lane)*8];
            acc[0][ct] = __builtin_amdgcn_mfma_f32_16x16x32_bf16(a0, b, acc[0][ct], 0, 0, 0);
            acc[1][ct] = __builtin_amdgcn_mfma_f32_16x16x32_bf16(a1, b, acc[1][ct], 0, 0, 0);
        }
    }

    // bias + LN stats
    f32x4 s[2], q[2];
    #pragma unroll
    for (int rt = 0; rt < 2; ++rt) {
        #pragma unroll
        for (int ct = 0; ct < 4; ++ct) acc[rt][ct] += b1v[ct];
        s[rt] = acc[rt][0] + acc[rt][1] + acc[rt][2] + acc[rt][3];
        q[rt] = acc[rt][0]*acc[rt][0] + acc[rt][1]*acc[rt][1]
              + acc[rt][2]*acc[rt][2] + acc[rt][3]*acc[rt][3];
    }
    #pragma unroll
    for (int off = 1; off <= 8; off <<= 1) {
        #pragma unroll
        for (int rt = 0; rt < 2; ++rt)
            #pragma unroll
            for (int j = 0; j < 4; ++j) {
                s[rt][j] += __shfl_xor(s[rt][j], off);
                q[rt][j] += __shfl_xor(q[rt][j], off);
            }
    }
    if (ll == 0) {
        #pragma unroll
        for (int rt = 0; rt < 2; ++rt)
            #pragma unroll
            for (int j = 0; j < 4; ++j) {
                red[w][rt*16 + lg*4 + j][0] = s[rt][j];
                red[w][rt*16 + lg*4 + j][1] = q[rt][j];
            }
    }
    __syncthreads();

    // LN + SiLU -> Sl (overlays AeG)
    #pragma unroll
    for (int rt = 0; rt < 2; ++rt) {
        #pragma unroll
        for (int j = 0; j < 4; ++j) {
            const int lr = rt*16 + lg*4 + j;
            const float S = red[2*wr][lr][0] + red[2*wr + 1][lr][0];
            const float Q = red[2*wr][lr][1] + red[2*wr + 1][lr][1];
            const float mu = S * (1.0f/DD);
            const float var = Q * (1.0f/DD) - mu*mu;
            const float inv = rsqrtf(var + 1e-5f);
            #pragma unroll
            for (int ct = 0; ct < 4; ++ct) {
                const float hn = (acc[rt][ct][j] - mu) * inv * g1v[ct] + be1v[ct];
                const float sv = hn / (1.0f + __expf(-hn));
                AeG[R0 + lr][C0 + ct*16 + ll] = f2bf(sv);
            }
        }
    }
    __syncthreads();

    // GEMM2: [64x128] @ [128x128]
    f32x4 acc2[2][4] = {};
    #pragma unroll
    for (int kt = 0; kt < 4; ++kt) {
        const v8bf a0 = *(const v8bf*)&AeG[R0 + ll][kt*32 + lg*8];
        const v8bf a1 = *(const v8bf*)&AeG[R0 + 16 + ll][kt*32 + lg*8];
        #pragma unroll
        for (int ct = 0; ct < 4; ++ct) {
            const v8bf b = *(const v8bf*)&Wp2[((kt*8 + wc*4 + ct)*64 + lane)*8];
            acc2[0][ct] = __builtin_amdgcn_mfma_f32_16x16x32_bf16(a0, b, acc2[0][ct], 0, 0, 0);
            acc2[1][ct] = __builtin_amdgcn_mfma_f32_16x16x32_bf16(a1, b, acc2[1][ct], 0, 0, 0);
        }
    }

    // residual from LDS tile + store
    #pragma unroll
    for (int rt = 0; rt < 2; ++rt)
        #pragma unroll
        for (int ct = 0; ct < 4; ++ct)
            #pragma unroll
            for (int j = 0; j < 4; ++j) {
                const int lr = rt*16 + lg*4 + j;
                const int col = C0 + ct*16 + ll;
                const float res = bf2f(AeE[R0 + lr][col]);
                const float v = res + acc2[rt][ct][j] + b2v[ct];
                if constexpr (sizeof(TOUT) == 4) e_out[(base + R0 + lr)*DD + col] = v;
                else                             e_out[(base + R0 + lr)*DD + col] = f2bf(v);
            }
}

// ---------------------------------------------------------------------------
// Node MLP (MFMA) with fused CSR gather-aggregate, templated on e dtype.
// ---------------------------------------------------------------------------
template <typename TE>
__global__ __launch_bounds__(256)
void node_mlp(const float* n_in, const TE* __restrict__ e_buf,
              const int* __restrict__ off, const int* __restrict__ elist,
              const unsigned short* __restrict__ Wp1,
              const float* __restrict__ b1, const float* __restrict__ g1,
              const float* __restrict__ be1,
              const unsigned short* __restrict__ Wp2,
              const float* __restrict__ b2, float* n_out)
{
    __shared__ __align__(16) unsigned short AnN[64][136];
    __shared__ __align__(16) unsigned short AnG[64][136];
    __shared__ float red[4][32][2];

    const int tid = threadIdx.x;
    const long base = (long)blockIdx.x * 64;

    const int lane = tid & 63, w = tid >> 6;
    const int wr = w >> 1, wc = w & 1;
    const int R0 = wr*32, C0 = wc*64;
    const int lg = lane >> 4, ll = lane & 15;

    float b1v[4], g1v[4], be1v[4], b2v[4];
    #pragma unroll
    for (int ct = 0; ct < 4; ++ct) {
        const int c = C0 + ct*16 + ll;
        b1v[ct] = b1[c]; g1v[ct] = g1[c]; be1v[ct] = be1[c]; b2v[ct] = b2[c];
    }

    // gather-aggregate: 4 threads/row x 32 cols
    {
        const int r  = tid >> 2;
        const int cq = (tid & 3) * 32;
        const long row = base + r;
        float a[32];
        #pragma unroll
        for (int q = 0; q < 32; ++q) a[q] = 0.f;
        if (row < NODES) {
            const int jb = off[row], je = off[row + 1];
            for (int j = jb; j < je; ++j) {
                if constexpr (sizeof(TE) == 4) {
                    const float* p = (const float*)&e_buf[(long)elist[j]*DD + cq];
                    #pragma unroll
                    for (int q = 0; q < 8; ++q) {
                        const float4 v = *(const float4*)(p + q*4);
                        a[q*4+0] += v.x; a[q*4+1] += v.y;
                        a[q*4+2] += v.z; a[q*4+3] += v.w;
                    }
                } else {
                    const unsigned short* p = (const unsigned short*)&e_buf[(long)elist[j]*DD + cq];
                    #pragma unroll
                    for (int u = 0; u < 4; ++u) {
                        const uint4 v = *(const uint4*)(p + u*8);
                        a[u*8+0] += bf2f((unsigned short)(v.x & 0xffff));
                        a[u*8+1] += bf2f((unsigned short)(v.x >> 16));
                        a[u*8+2] += bf2f((unsigned short)(v.y & 0xffff));
                        a[u*8+3] += bf2f((unsigned short)(v.y >> 16));
                        a[u*8+4] += bf2f((unsigned short)(v.z & 0xffff));
                        a[u*8+5] += bf2f((unsigned short)(v.z >> 16));
                        a[u*8+6] += bf2f((unsigned short)(v.w & 0xffff));
                        a[u*8+7] += bf2f((unsigned short)(v.w >> 16));
                    }
                }
            }
        }
        #pragma unroll
        for (int q = 0; q < 8; ++q) {
            ushort4 o;
            o.x = f2bf(a[q*4+0]); o.y = f2bf(a[q*4+1]);
            o.z = f2bf(a[q*4+2]); o.w = f2bf(a[q*4+3]);
            *(ushort4*)&AnG[r][cq + q*4] = o;
        }
    }

    // stage n tile
    #pragma unroll
    for (int it = 0; it < 8; ++it) {
        const int i = tid + it*256;
        const int row = i >> 5;
        const int c = (i & 31) * 4;
        float4 v = {0.f, 0.f, 0.f, 0.f};
        if (base + row < NODES) v = *(const float4*)&n_in[(base + row)*DD + c];
        ushort4 o; o.x = f2bf(v.x); o.y = f2bf(v.y); o.z = f2bf(v.z); o.w = f2bf(v.w);
        *(ushort4*)&AnN[row][c] = o;
    }
    __syncthreads();

    // GEMM1: [64x256] @ [256x128]
    f32x4 acc[2][4] = {};
    #pragma unroll
    for (int kt = 0; kt < 8; ++kt) {
        const unsigned short* a0p = (kt < 4) ? &AnN[R0 + ll][kt*32 + lg*8]
                                             : &AnG[R0 + ll][(kt-4)*32 + lg*8];
        const unsigned short* a1p = (kt < 4) ? &AnN[R0 + 16 + ll][kt*32 + lg*8]
                                             : &AnG[R0 + 16 + ll][(kt-4)*32 + lg*8];
        const v8bf a0 = *(const v8bf*)a0p;
        const v8bf a1 = *(const v8bf*)a1p;
        #pragma unroll
        for (int ct = 0; ct < 4; ++ct) {
            const v8bf b = *(const v8bf*)&Wp1[((kt*8 + wc*4 + ct)*64 + lane)*8];
            acc[0][ct] = __builtin_amdgcn_mfma_f32_16x16x32_bf16(a0, b, acc[0][ct], 0, 0, 0);
            acc[1][ct] = __builtin_amdgcn_mfma_f32_16x16x32_bf16(a1, b, acc[1][ct], 0, 0, 0);
        }
    }

    f32x4 s[2], q[2];
    #pragma unroll
    for (int rt = 0; rt < 2; ++rt) {
        #pragma unroll
        for (int ct = 0; ct < 4; ++ct) acc[rt][ct] += b1v[ct];
        s[rt] = acc[rt][0] + acc[rt][1] + acc[rt][2] + acc[rt][3];
        q[rt] = acc[rt][0]*acc[rt][0] + acc[rt][1]*acc[rt][1]
              + acc[rt][2]*acc[rt][2] + acc[rt][3]*acc[rt][3];
    }
    #pragma unroll
    for (int off_ = 1; off_ <= 8; off_ <<= 1) {
        #pragma unroll
        for (int rt = 0; rt < 2; ++rt)
            #pragma unroll
            for (int j = 0; j < 4; ++j) {
                s[rt][j] += __shfl_xor(s[rt][j], off_);
                q[rt][j] += __shfl_xor(q[rt][j], off_);
            }
    }
    if (ll == 0) {
        #pragma unroll
        for (int rt = 0; rt < 2; ++rt)
            #pragma unroll
            for (int j = 0; j < 4; ++j) {
                red[w][rt*16 + lg*4 + j][0] = s[rt][j];
                red[w][rt*16 + lg*4 + j][1] = q[rt][j];
            }
    }
    __syncthreads();

    #pragma unroll
    for (int rt = 0; rt < 2; ++rt) {
        #pragma unroll
        for (int j = 0; j < 4; ++j) {
            const int lr = rt*16 + lg*4 + j;
            const float S = red[2*wr][lr][0] + red[2*wr + 1][lr][0];
            const float Q = red[2*wr][lr][1] + red[2*wr + 1][lr][1];
            const float mu = S * (1.0f/DD);
            const float var = Q * (1.0f/DD) - mu*mu;
            const float inv = rsqrtf(var + 1e-5f);
            #pragma unroll
            for (int ct = 0; ct < 4; ++ct) {
                const float hn = (acc[rt][ct][j] - mu) * inv * g1v[ct] + be1v[ct];
                const float sv = hn / (1.0f + __expf(-hn));
                AnG[R0 + lr][C0 + ct*16 + ll] = f2bf(sv);
            }
        }
    }
    __syncthreads();

    f32x4 acc2[2][4] = {};
    #pragma unroll
    for (int kt = 0; kt < 4; ++kt) {
        const v8bf a0 = *(const v8bf*)&AnG[R0 + ll][kt*32 + lg*8];
        const v8bf a1 = *(const v8bf*)&AnG[R0 + 16 + ll][kt*32 + lg*8];
        #pragma unroll
        for (int ct = 0; ct < 4; ++ct) {
            const v8bf b = *(const v8bf*)&Wp2[((kt*8 + wc*4 + ct)*64 + lane)*8];
            acc2[0][ct] = __builtin_amdgcn_mfma_f32_16x16x32_bf16(a0, b, acc2[0][ct], 0, 0, 0);
            acc2[1][ct] = __builtin_amdgcn_mfma_f32_16x16x32_bf16(a1, b, acc2[1][ct], 0, 0, 0);
        }
    }

    #pragma unroll
    for (int rt = 0; rt < 2; ++rt)
        #pragma unroll
        for (int ct = 0; ct < 4; ++ct)
            #pragma unroll
            for (int j = 0; j < 4; ++j) {
                const long grow = base + R0 + rt*16 + lg*4 + j;
                if (grow < NODES) {
                    const int col = C0 + ct*16 + ll;
                    n_out[grow*DD + col] = n_in[grow*DD + col] + acc2[rt][ct][j] + b2v[ct];
                }
            }
}

extern "C" void kernel_launch(void* const* d_in, const int* in_sizes, int n_in,
                              void* d_out, int out_size, void* d_ws, size_t ws_size,
                              hipStream_t stream) {
    const float* node_feat = (const float*)d_in[0];
    const float* edge_attr = (const float*)d_in[1];
    const int*   edge_index= (const int*)d_in[2];
    const float* eW1 = (const float*)d_in[3];
    const float* eb1 = (const float*)d_in[4];
    const float* eg1 = (const float*)d_in[5];
    const float* ebe1= (const float*)d_in[6];
    const float* eW2 = (const float*)d_in[7];
    const float* eb2 = (const float*)d_in[8];
    const float* nW1 = (const float*)d_in[9];
    const float* nb1 = (const float*)d_in[10];
    const float* ng1 = (const float*)d_in[11];
    const float* nbe1= (const float*)d_in[12];
    const float* nW2 = (const float*)d_in[13];
    const float* nb2 = (const float*)d_in[14];

    const int N = NODES, E = EDGES;
    const int* src  = edge_index;
    const int* dstI = edge_index + E;

    float* out_n = (float*)d_out;
    float* out_e = (float*)d_out + (size_t)N * DD;

    // ws: [wp 458752 B][deg 50000][off 50001][cursor 50000][elist 256000] ints
    //     [e1w 65.536 MB bf16, if ws_size permits]
    unsigned short* wp = (unsigned short*)d_ws;
    int* ib     = (int*)((char*)d_ws + 458752);
    int* deg    = ib;
    int* off    = ib + 50000;
    int* cursor = ib + 100001;
    int* elist  = ib + 150001;
    unsigned short* e1w = (unsigned short*)((char*)d_ws + 2082816);
    const bool use_bf16_e1 = ws_size >= (2082816ull + (size_t)EDGES*DD*2 + 64);

    pack_weights<<<56, 512, 0, stream>>>(eW1, eW2, nW1, nW2, wp);

    hipMemsetAsync(deg, 0, (size_t)N * sizeof(int), stream);
    hist_kernel<<<(E + 255)/256, 256, 0, stream>>>(dstI, deg);
    scan_deg<<<1, 1024, 0, stream>>>(deg, off, cursor);
    place_kernel<<<(E + 255)/256, 256, 0, stream>>>(dstI, cursor, elist);

    if (use_bf16_e1) {
        // layer 0: e1 stored as bf16 in ws
        edge_mlp<float, unsigned short><<<E/64, 256, 0, stream>>>(
            edge_attr, node_feat, src, dstI,
            wp, eb1, eg1, ebe1, wp + 98304, eb2, e1w);
        node_mlp<unsigned short><<<(N + 63)/64, 256, 0, stream>>>(
            node_feat, e1w, off, elist,
            wp + 131072, nb1, ng1, nbe1, wp + 196608, nb2, out_n);
        // layer 1: final e in fp32 d_out
        edge_mlp<unsigned short, float><<<E/64, 256, 0, stream>>>(
            e1w, out_n, src, dstI,
            wp + 49152, eb1 + DD, eg1 + DD, ebe1 + DD, wp + 98304 + 16384, eb2 + DD, out_e);
        node_mlp<float><<<(N + 63)/64, 256, 0, stream>>>(
            out_n, out_e, off, elist,
            wp + 131072 + 32768, nb1 + DD, ng1 + DD, nbe1 + DD,
            wp + 196608 + 16384, nb2 + DD, out_n);
    } else {
        // fallback: fp32 intermediate in d_out e-region (in-place layer 1)
        for (int l = 0; l < 2; ++l) {
            const float* ein = (l == 0) ? edge_attr : out_e;
            const float* nin = (l == 0) ? node_feat : out_n;
            edge_mlp<float, float><<<E/64, 256, 0, stream>>>(ein, nin, src, dstI,
                wp + l*49152, eb1 + l*DD, eg1 + l*DD, ebe1 + l*DD,
                wp + 98304 + l*16384, eb2 + l*DD, out_e);
            node_mlp<float><<<(N + 63)/64, 256, 0, stream>>>(nin, out_e, off, elist,
                wp + 131072 + l*32768, nb1 + l*DD, ng1 + l*DD, nbe1 + l*DD,
                wp + 196608 + l*16384, nb2 + l*DD, out_n);
        }
    }
}

// Round 6
// 462.143 us; speedup vs baseline: 4.6177x; 1.1032x over previous
//
#include <hip/hip_runtime.h>
#include <hip/hip_bf16.h>

typedef float f32x4 __attribute__((ext_vector_type(4)));
typedef __bf16 v8bf __attribute__((ext_vector_type(8)));
typedef unsigned short ushort_t;

#define DD 128
#define EDGES 256000
#define NODES 50000

__device__ __forceinline__ unsigned short f2bf(float f) {
    union { float f; unsigned u; } v; v.f = f;
    unsigned r = v.u + 0x7fffu + ((v.u >> 16) & 1u);
    return (unsigned short)(r >> 16);
}
__device__ __forceinline__ float bf2f(unsigned short u) {
    union { unsigned u; float f; } v; v.u = ((unsigned)u) << 16; return v.f;
}

// ---------------------------------------------------------------------------
// Weight prep. Packed B-fragment layout for a [K x C] matrix:
//   dst[((kt*(C/16)+ct)*64+l)*8+j] = bf16(W[(kt*32+(l>>4)*8+j)*C + ct*16+(l&15)])
// wp layout (ushorts, per-layer stride noted):
//   eW1a (rows 0-127 of e_W1, 128x128):   layer*16384          [0,32768)
//   eWbc (rows 128-383 as [128x256]):     32768+layer*32768    [32768,98304)
//   eW2:                                  98304+layer*16384
//   nW1 (256x128):                        131072+layer*32768
//   nW2:                                  196608+layer*16384
// ---------------------------------------------------------------------------
__global__ __launch_bounds__(512)
void pack_weights(const float* __restrict__ eW1, const float* __restrict__ eW2,
                  const float* __restrict__ nW1, const float* __restrict__ nW2,
                  unsigned short* __restrict__ wp)
{
    const int b = blockIdx.x;            // 0..47
    const int layer = b / 24;
    const int u = b % 24;
    const int t = threadIdx.x;
    const int ct0 = t >> 6, l = t & 63;
    const int lg = l >> 4, ll = l & 15;

    if (u < 8 && u >= 4) {
        // eWbc: [128 x 256], Wbc[k][c] = eW1[128 + k + (c>=128?128:0)][c&127]
        const int kt = u - 4;
        const float* W = eW1 + layer*49152;
        unsigned short* dst = wp + 32768 + layer*32768;
        #pragma unroll
        for (int h = 0; h < 2; ++h) {
            const int ct = ct0 + h*8;
            #pragma unroll
            for (int j = 0; j < 8; ++j) {
                const int k = kt*32 + lg*8 + j;
                const int cout = ct*16 + ll;
                const int row = 128 + k + ((cout >= 128) ? 128 : 0);
                const int col = cout & 127;
                dst[((kt*16 + ct)*64 + l)*8 + j] = f2bf(W[row*128 + col]);
            }
        }
        return;
    }
    const float* W; int kt; unsigned short* dst;
    if (u < 4)       { W = eW1 + layer*49152; kt = u;      dst = wp + layer*16384; }
    else if (u < 12) { W = eW2 + layer*16384; kt = u - 8;  dst = wp + 98304 + layer*16384; }
    else if (u < 20) { W = nW1 + layer*32768; kt = u - 12; dst = wp + 131072 + layer*32768; }
    else             { W = nW2 + layer*16384; kt = u - 20; dst = wp + 196608 + layer*16384; }
    #pragma unroll
    for (int j = 0; j < 8; ++j) {
        const int k = kt*32 + lg*8 + j;
        const int c = ct0*16 + ll;
        dst[((kt*8 + ct0)*64 + l)*8 + j] = f2bf(W[k*128 + c]);
    }
}

// ---------------------------------------------------------------------------
// CSR build
// ---------------------------------------------------------------------------
__global__ void hist_kernel(const int* __restrict__ dst, int* __restrict__ deg)
{
    const int i = blockIdx.x * blockDim.x + threadIdx.x;
    if (i < EDGES) atomicAdd(&deg[dst[i]], 1);
}

__global__ __launch_bounds__(1024)
void scan_deg(const int* __restrict__ deg, int* __restrict__ off,
              int* __restrict__ cursor)
{
    __shared__ int ls[1024];
    const int t = threadIdx.x;
    const int C = 49;
    const int start = t * C;
    int s = 0;
    for (int k = 0; k < C; ++k) {
        const int idx = start + k;
        if (idx < NODES) s += deg[idx];
    }
    ls[t] = s;
    __syncthreads();
    for (int d = 1; d < 1024; d <<= 1) {
        int v = 0;
        if (t >= d) v = ls[t - d];
        __syncthreads();
        if (t >= d) ls[t] += v;
        __syncthreads();
    }
    int base = (t == 0) ? 0 : ls[t - 1];
    for (int k = 0; k < C; ++k) {
        const int idx = start + k;
        if (idx < NODES) { off[idx] = base; cursor[idx] = base; base += deg[idx]; }
    }
    if (t == 1023) off[NODES] = EDGES;
}

__global__ void place_kernel(const int* __restrict__ dst, int* __restrict__ cursor,
                             int* __restrict__ elist)
{
    const int i = blockIdx.x * blockDim.x + threadIdx.x;
    if (i < EDGES) {
        const int p = atomicAdd(&cursor[dst[i]], 1);
        elist[p] = i;
    }
}

// ---------------------------------------------------------------------------
// Node projection: NG[v] = bf16(n[v] @ Wbc)  -> [NODES x 256] bf16
// ---------------------------------------------------------------------------
__global__ __launch_bounds__(256)
void node_proj(const float* __restrict__ n,
               const unsigned short* __restrict__ Wbc,
               unsigned short* __restrict__ NG)
{
    __shared__ __align__(16) unsigned short A[64][136];
    const int tid = threadIdx.x;
    const long base = (long)blockIdx.x * 64;

    #pragma unroll
    for (int it = 0; it < 8; ++it) {
        const int i = tid + it*256;
        const int row = i >> 5;
        const int c = (i & 31) * 4;
        float4 v = {0.f, 0.f, 0.f, 0.f};
        if (base + row < NODES) v = *(const float4*)&n[(base + row)*DD + c];
        ushort4 o; o.x = f2bf(v.x); o.y = f2bf(v.y); o.z = f2bf(v.z); o.w = f2bf(v.w);
        *(ushort4*)&A[row][c] = o;
    }
    __syncthreads();

    const int lane = tid & 63, w = tid >> 6;
    const int wr = w >> 1, wc = w & 1;
    const int R0 = wr*32, C0w = wc*128;
    const int lg = lane >> 4, ll = lane & 15;

    f32x4 acc[2][8] = {};
    #pragma unroll
    for (int kt = 0; kt < 4; ++kt) {
        const v8bf a0 = *(const v8bf*)&A[R0 + ll][kt*32 + lg*8];
        const v8bf a1 = *(const v8bf*)&A[R0 + 16 + ll][kt*32 + lg*8];
        #pragma unroll
        for (int ct = 0; ct < 8; ++ct) {
            const v8bf b = *(const v8bf*)&Wbc[((kt*16 + wc*8 + ct)*64 + lane)*8];
            acc[0][ct] = __builtin_amdgcn_mfma_f32_16x16x32_bf16(a0, b, acc[0][ct], 0, 0, 0);
            acc[1][ct] = __builtin_amdgcn_mfma_f32_16x16x32_bf16(a1, b, acc[1][ct], 0, 0, 0);
        }
    }

    #pragma unroll
    for (int rt = 0; rt < 2; ++rt)
        #pragma unroll
        for (int ct = 0; ct < 8; ++ct)
            #pragma unroll
            for (int j = 0; j < 4; ++j) {
                const long grow = base + R0 + rt*16 + lg*4 + j;
                if (grow < NODES)
                    NG[grow*256 + C0w + ct*16 + ll] = f2bf(acc[rt][ct][j]);
            }
}

// ---------------------------------------------------------------------------
// Edge MLP with precomputed node projections. Processes edges in dst-sorted
// (permuted) order p; e rows stored permuted.
//   acc = eP @ W1a + NG[src][0:128] + NG[dst][128:256] (+b1) -> LN -> SiLU
//   out = bf16 residual + @W2 + b2
// L0: e_in = edge_attr fp32, original order via eidx; out: ePw bf16 (permuted)
// L1: e_in = e1w bf16 permuted (direct); out: ePw bf16 in-place + e_out fp32
//     scattered to original order.
// LDS: AeE 17408 + Sl 17408 + red 1024 + idx 768 = 36.6KB -> 4 blocks/CU
// ---------------------------------------------------------------------------
template <bool L0>
__global__ __launch_bounds__(256, 4)
void edge_mlp_ng(const void* __restrict__ e_in_v,
                 const unsigned short* __restrict__ NG,
                 const int* __restrict__ elist,
                 const int* __restrict__ srcA, const int* __restrict__ dstA,
                 const unsigned short* __restrict__ Wa,
                 const float* __restrict__ b1, const float* __restrict__ g1,
                 const float* __restrict__ be1,
                 const unsigned short* __restrict__ Wp2,
                 const float* __restrict__ b2,
                 unsigned short* __restrict__ ePw,
                 float* __restrict__ e_out)
{
    __shared__ __align__(16) unsigned short AeE[64][136];
    __shared__ __align__(16) unsigned short Sl[64][136];
    __shared__ float red[4][32][2];
    __shared__ int eidx[64], sidx[64], didx[64];

    const int tid = threadIdx.x;
    const long base = (long)blockIdx.x * 64;

    if (tid < 64) {
        const int i = elist[base + tid];
        eidx[tid] = i; sidx[tid] = srcA[i]; didx[tid] = dstA[i];
    }
    __syncthreads();

    const int lane = tid & 63, w = tid >> 6;
    const int wr = w >> 1, wc = w & 1;
    const int R0 = wr*32, C0 = wc*64;
    const int lg = lane >> 4, ll = lane & 15;

    // stage e tile
    if constexpr (L0) {
        const float* e_in = (const float*)e_in_v;
        #pragma unroll
        for (int it = 0; it < 8; ++it) {
            const int i = tid + it*256;
            const int row = i >> 5;
            const int c = (i & 31) * 4;
            const float4 v = *(const float4*)&e_in[(long)eidx[row]*DD + c];
            ushort4 o; o.x = f2bf(v.x); o.y = f2bf(v.y); o.z = f2bf(v.z); o.w = f2bf(v.w);
            *(ushort4*)&AeE[row][c] = o;
        }
    } else {
        const unsigned short* e_in = (const unsigned short*)e_in_v;
        #pragma unroll
        for (int it = 0; it < 4; ++it) {
            const int i = tid + it*256;
            const int row = i >> 4;
            const int c = (i & 15) * 8;
            *(uint4*)&AeE[row][c] = *(const uint4*)&e_in[(base + row)*DD + c];
        }
    }
    __syncthreads();

    float b1v[4], g1v[4], be1v[4], b2v[4];
    #pragma unroll
    for (int ct = 0; ct < 4; ++ct) {
        const int c = C0 + ct*16 + ll;
        b1v[ct] = b1[c]; g1v[ct] = g1[c]; be1v[ct] = be1[c]; b2v[ct] = b2[c];
    }

    // GEMM1a: eP @ W1a (K=128)
    f32x4 acc[2][4] = {};
    #pragma unroll
    for (int kt = 0; kt < 4; ++kt) {
        const v8bf a0 = *(const v8bf*)&AeE[R0 + ll][kt*32 + lg*8];
        const v8bf a1 = *(const v8bf*)&AeE[R0 + 16 + ll][kt*32 + lg*8];
        #pragma unroll
        for (int ct = 0; ct < 4; ++ct) {
            const v8bf b = *(const v8bf*)&Wa[((kt*8 + wc*4 + ct)*64 + lane)*8];
            acc[0][ct] = __builtin_amdgcn_mfma_f32_16x16x32_bf16(a0, b, acc[0][ct], 0, 0, 0);
            acc[1][ct] = __builtin_amdgcn_mfma_f32_16x16x32_bf16(a1, b, acc[1][ct], 0, 0, 0);
        }
    }

    // + NG[src][col] + NG[dst][128+col]
    #pragma unroll
    for (int rt = 0; rt < 2; ++rt) {
        #pragma unroll
        for (int j = 0; j < 4; ++j) {
            const int lr = rt*16 + lg*4 + j;
            const long sid = sidx[R0 + lr];
            const long did = didx[R0 + lr];
            const unsigned short* pb = NG + sid*256 + C0 + ll;
            const unsigned short* pc = NG + did*256 + 128 + C0 + ll;
            #pragma unroll
            for (int ct = 0; ct < 4; ++ct)
                acc[rt][ct][j] += bf2f(pb[ct*16]) + bf2f(pc[ct*16]);
        }
    }

    // bias + LN stats
    f32x4 s[2], q[2];
    #pragma unroll
    for (int rt = 0; rt < 2; ++rt) {
        #pragma unroll
        for (int ct = 0; ct < 4; ++ct) acc[rt][ct] += b1v[ct];
        s[rt] = acc[rt][0] + acc[rt][1] + acc[rt][2] + acc[rt][3];
        q[rt] = acc[rt][0]*acc[rt][0] + acc[rt][1]*acc[rt][1]
              + acc[rt][2]*acc[rt][2] + acc[rt][3]*acc[rt][3];
    }
    #pragma unroll
    for (int off = 1; off <= 8; off <<= 1) {
        #pragma unroll
        for (int rt = 0; rt < 2; ++rt)
            #pragma unroll
            for (int j = 0; j < 4; ++j) {
                s[rt][j] += __shfl_xor(s[rt][j], off);
                q[rt][j] += __shfl_xor(q[rt][j], off);
            }
    }
    if (ll == 0) {
        #pragma unroll
        for (int rt = 0; rt < 2; ++rt)
            #pragma unroll
            for (int j = 0; j < 4; ++j) {
                red[w][rt*16 + lg*4 + j][0] = s[rt][j];
                red[w][rt*16 + lg*4 + j][1] = q[rt][j];
            }
    }
    __syncthreads();

    // LN + SiLU -> Sl
    #pragma unroll
    for (int rt = 0; rt < 2; ++rt) {
        #pragma unroll
        for (int j = 0; j < 4; ++j) {
            const int lr = rt*16 + lg*4 + j;
            const float S = red[2*wr][lr][0] + red[2*wr + 1][lr][0];
            const float Q = red[2*wr][lr][1] + red[2*wr + 1][lr][1];
            const float mu = S * (1.0f/DD);
            const float var = Q * (1.0f/DD) - mu*mu;
            const float inv = rsqrtf(var + 1e-5f);
            #pragma unroll
            for (int ct = 0; ct < 4; ++ct) {
                const float hn = (acc[rt][ct][j] - mu) * inv * g1v[ct] + be1v[ct];
                const float sv = hn / (1.0f + __expf(-hn));
                Sl[R0 + lr][C0 + ct*16 + ll] = f2bf(sv);
            }
        }
    }
    __syncthreads();

    // GEMM2
    f32x4 acc2[2][4] = {};
    #pragma unroll
    for (int kt = 0; kt < 4; ++kt) {
        const v8bf a0 = *(const v8bf*)&Sl[R0 + ll][kt*32 + lg*8];
        const v8bf a1 = *(const v8bf*)&Sl[R0 + 16 + ll][kt*32 + lg*8];
        #pragma unroll
        for (int ct = 0; ct < 4; ++ct) {
            const v8bf b = *(const v8bf*)&Wp2[((kt*8 + wc*4 + ct)*64 + lane)*8];
            acc2[0][ct] = __builtin_amdgcn_mfma_f32_16x16x32_bf16(a0, b, acc2[0][ct], 0, 0, 0);
            acc2[1][ct] = __builtin_amdgcn_mfma_f32_16x16x32_bf16(a1, b, acc2[1][ct], 0, 0, 0);
        }
    }

    // residual + store (permuted bf16 always; scattered fp32 on layer 1)
    #pragma unroll
    for (int rt = 0; rt < 2; ++rt)
        #pragma unroll
        for (int ct = 0; ct < 4; ++ct)
            #pragma unroll
            for (int j = 0; j < 4; ++j) {
                const int lr = rt*16 + lg*4 + j;
                const int col = C0 + ct*16 + ll;
                const float v = bf2f(AeE[R0 + lr][col]) + acc2[rt][ct][j] + b2v[ct];
                ePw[(base + R0 + lr)*DD + col] = f2bf(v);
                if constexpr (!L0)
                    e_out[(long)eidx[R0 + lr]*DD + col] = v;
            }
}

// ---------------------------------------------------------------------------
// Old-style edge MLP (fallback for layer 1 when ws too small for NG1):
// full 384-K GEMM with n gathers. e input = permuted bf16 e1w; writes
// fp32 e_out scattered to original order.
// ---------------------------------------------------------------------------
__global__ __launch_bounds__(256, 4)
void edge_mlp_full(const unsigned short* __restrict__ e_in,
                   const float* __restrict__ nf,
                   const int* __restrict__ elist,
                   const int* __restrict__ srcA, const int* __restrict__ dstA,
                   const unsigned short* __restrict__ Wa,
                   const unsigned short* __restrict__ Wbc,
                   const float* __restrict__ b1, const float* __restrict__ g1,
                   const float* __restrict__ be1,
                   const unsigned short* __restrict__ Wp2,
                   const float* __restrict__ b2, float* __restrict__ e_out)
{
    __shared__ __align__(16) unsigned short AeE[64][136];
    __shared__ __align__(16) unsigned short AeG[64][132];
    __shared__ float red[4][32][2];
    __shared__ int eidx[64], sidx[64], didx[64];

    const int tid = threadIdx.x;
    const long base = (long)blockIdx.x * 64;

    if (tid < 64) {
        const int i = elist[base + tid];
        eidx[tid] = i; sidx[tid] = srcA[i]; didx[tid] = dstA[i];
    }

    const int lane = tid & 63, w = tid >> 6;
    const int wr = w >> 1, wc = w & 1;
    const int R0 = wr*32, C0 = wc*64;
    const int lg = lane >> 4, ll = lane & 15;

    #pragma unroll
    for (int it = 0; it < 4; ++it) {
        const int i = tid + it*256;
        const int row = i >> 4;
        const int c = (i & 15) * 8;
        *(uint4*)&AeE[row][c] = *(const uint4*)&e_in[(base + row)*DD + c];
    }
    __syncthreads();

    // src gather -> AeG
    #pragma unroll
    for (int it = 0; it < 8; ++it) {
        const int i = tid + it*256;
        const int row = i >> 5;
        const int c = (i & 31) * 4;
        const float4 v = *(const float4*)&nf[(long)sidx[row]*DD + c];
        ushort4 o; o.x = f2bf(v.x); o.y = f2bf(v.y); o.z = f2bf(v.z); o.w = f2bf(v.w);
        *(ushort4*)&AeG[row][c] = o;
    }
    // dst gather -> regs
    float4 dreg[8];
    #pragma unroll
    for (int it = 0; it < 8; ++it) {
        const int i = tid + it*256;
        const int row = i >> 5;
        const int c = (i & 31) * 4;
        dreg[it] = *(const float4*)&nf[(long)didx[row]*DD + c];
    }
    __syncthreads();

    float b1v[4], g1v[4], be1v[4], b2v[4];
    #pragma unroll
    for (int ct = 0; ct < 4; ++ct) {
        const int c = C0 + ct*16 + ll;
        b1v[ct] = b1[c]; g1v[ct] = g1[c]; be1v[ct] = be1[c]; b2v[ct] = b2[c];
    }

    f32x4 acc[2][4] = {};
    #pragma unroll
    for (int kt = 0; kt < 8; ++kt) {
        const unsigned short* a0p = (kt < 4) ? &AeE[R0 + ll][kt*32 + lg*8]
                                             : &AeG[R0 + ll][(kt-4)*32 + lg*8];
        const unsigned short* a1p = (kt < 4) ? &AeE[R0 + 16 + ll][kt*32 + lg*8]
                                             : &AeG[R0 + 16 + ll][(kt-4)*32 + lg*8];
        const v8bf a0 = *(const v8bf*)a0p;
        const v8bf a1 = *(const v8bf*)a1p;
        #pragma unroll
        for (int ct = 0; ct < 4; ++ct) {
            const v8bf b = (kt < 4)
                ? *(const v8bf*)&Wa[((kt*8 + wc*4 + ct)*64 + lane)*8]
                : *(const v8bf*)&Wbc[(((kt-4)*16 + wc*4 + ct)*64 + lane)*8];
            acc[0][ct] = __builtin_amdgcn_mfma_f32_16x16x32_bf16(a0, b, acc[0][ct], 0, 0, 0);
            acc[1][ct] = __builtin_amdgcn_mfma_f32_16x16x32_bf16(a1, b, acc[1][ct], 0, 0, 0);
        }
    }
    __syncthreads();

    #pragma unroll
    for (int it = 0; it < 8; ++it) {
        const int i = tid + it*256;
        const int row = i >> 5;
        const int c = (i & 31) * 4;
        ushort4 o; o.x = f2bf(dreg[it].x); o.y = f2bf(dreg[it].y);
        o.z = f2bf(dreg[it].z); o.w = f2bf(dreg[it].w);
        *(ushort4*)&AeG[row][c] = o;
    }
    __syncthreads();

    #pragma unroll
    for (int kt = 0; kt < 4; ++kt) {
        const v8bf a0 = *(const v8bf*)&AeG[R0 + ll][kt*32 + lg*8];
        const v8bf a1 = *(const v8bf*)&AeG[R0 + 16 + ll][kt*32 + lg*8];
        #pragma unroll
        for (int ct = 0; ct < 4; ++ct) {
            const v8bf b = *(const v8bf*)&Wbc[((kt*16 + 8 + wc*4 + ct)*64 + lane)*8];
            acc[0][ct] = __builtin_amdgcn_mfma_f32_16x16x32_bf16(a0, b, acc[0][ct], 0, 0, 0);
            acc[1][ct] = __builtin_amdgcn_mfma_f32_16x16x32_bf16(a1, b, acc[1][ct], 0, 0, 0);
        }
    }

    f32x4 s[2], q[2];
    #pragma unroll
    for (int rt = 0; rt < 2; ++rt) {
        #pragma unroll
        for (int ct = 0; ct < 4; ++ct) acc[rt][ct] += b1v[ct];
        s[rt] = acc[rt][0] + acc[rt][1] + acc[rt][2] + acc[rt][3];
        q[rt] = acc[rt][0]*acc[rt][0] + acc[rt][1]*acc[rt][1]
              + acc[rt][2]*acc[rt][2] + acc[rt][3]*acc[rt][3];
    }
    #pragma unroll
    for (int off = 1; off <= 8; off <<= 1) {
        #pragma unroll
        for (int rt = 0; rt < 2; ++rt)
            #pragma unroll
            for (int j = 0; j < 4; ++j) {
                s[rt][j] += __shfl_xor(s[rt][j], off);
                q[rt][j] += __shfl_xor(q[rt][j], off);
            }
    }
    if (ll == 0) {
        #pragma unroll
        for (int rt = 0; rt < 2; ++rt)
            #pragma unroll
            for (int j = 0; j < 4; ++j) {
                red[w][rt*16 + lg*4 + j][0] = s[rt][j];
                red[w][rt*16 + lg*4 + j][1] = q[rt][j];
            }
    }
    __syncthreads();

    #pragma unroll
    for (int rt = 0; rt < 2; ++rt) {
        #pragma unroll
        for (int j = 0; j < 4; ++j) {
            const int lr = rt*16 + lg*4 + j;
            const float S = red[2*wr][lr][0] + red[2*wr + 1][lr][0];
            const float Q = red[2*wr][lr][1] + red[2*wr + 1][lr][1];
            const float mu = S * (1.0f/DD);
            const float var = Q * (1.0f/DD) - mu*mu;
            const float inv = rsqrtf(var + 1e-5f);
            #pragma unroll
            for (int ct = 0; ct < 4; ++ct) {
                const float hn = (acc[rt][ct][j] - mu) * inv * g1v[ct] + be1v[ct];
                const float sv = hn / (1.0f + __expf(-hn));
                AeG[R0 + lr][C0 + ct*16 + ll] = f2bf(sv);
            }
        }
    }
    __syncthreads();

    f32x4 acc2[2][4] = {};
    #pragma unroll
    for (int kt = 0; kt < 4; ++kt) {
        const v8bf a0 = *(const v8bf*)&AeG[R0 + ll][kt*32 + lg*8];
        const v8bf a1 = *(const v8bf*)&AeG[R0 + 16 + ll][kt*32 + lg*8];
        #pragma unroll
        for (int ct = 0; ct < 4; ++ct) {
            const v8bf b = *(const v8bf*)&Wp2[((kt*8 + wc*4 + ct)*64 + lane)*8];
            acc2[0][ct] = __builtin_amdgcn_mfma_f32_16x16x32_bf16(a0, b, acc2[0][ct], 0, 0, 0);
            acc2[1][ct] = __builtin_amdgcn_mfma_f32_16x16x32_bf16(a1, b, acc2[1][ct], 0, 0, 0);
        }
    }

    #pragma unroll
    for (int rt = 0; rt < 2; ++rt)
        #pragma unroll
        for (int ct = 0; ct < 4; ++ct)
            #pragma unroll
            for (int j = 0; j < 4; ++j) {
                const int lr = rt*16 + lg*4 + j;
                const int col = C0 + ct*16 + ll;
                const float v = bf2f(AeE[R0 + lr][col]) + acc2[rt][ct][j] + b2v[ct];
                e_out[(long)eidx[R0 + lr]*DD + col] = v;
            }
}

// ---------------------------------------------------------------------------
// Node MLP with CSR gather-aggregate.
// SEQ=true: e_buf = permuted bf16 rows, sequential [off[v],off[v+1]) reads.
// SEQ=false: e_buf = fp32 rows in original order via elist indirection.
// ---------------------------------------------------------------------------
template <bool SEQ>
__global__ __launch_bounds__(256)
void node_mlp(const float* n_in, const void* __restrict__ e_buf_v,
              const int* __restrict__ off, const int* __restrict__ elist,
              const unsigned short* __restrict__ Wp1,
              const float* __restrict__ b1, const float* __restrict__ g1,
              const float* __restrict__ be1,
              const unsigned short* __restrict__ Wp2,
              const float* __restrict__ b2, float* n_out)
{
    __shared__ __align__(16) unsigned short AnN[64][136];
    __shared__ __align__(16) unsigned short AnG[64][136];
    __shared__ float red[4][32][2];

    const int tid = threadIdx.x;
    const long base = (long)blockIdx.x * 64;

    const int lane = tid & 63, w = tid >> 6;
    const int wr = w >> 1, wc = w & 1;
    const int R0 = wr*32, C0 = wc*64;
    const int lg = lane >> 4, ll = lane & 15;

    float b1v[4], g1v[4], be1v[4], b2v[4];
    #pragma unroll
    for (int ct = 0; ct < 4; ++ct) {
        const int c = C0 + ct*16 + ll;
        b1v[ct] = b1[c]; g1v[ct] = g1[c]; be1v[ct] = be1[c]; b2v[ct] = b2[c];
    }

    // gather-aggregate: 4 threads/row x 32 cols
    {
        const int r  = tid >> 2;
        const int cq = (tid & 3) * 32;
        const long row = base + r;
        float a[32];
        #pragma unroll
        for (int q = 0; q < 32; ++q) a[q] = 0.f;
        if (row < NODES) {
            const int jb = off[row], je = off[row + 1];
            for (int j = jb; j < je; ++j) {
                if constexpr (SEQ) {
                    const unsigned short* p = (const unsigned short*)e_buf_v + (long)j*DD + cq;
                    #pragma unroll
                    for (int u = 0; u < 4; ++u) {
                        const uint4 v = *(const uint4*)(p + u*8);
                        a[u*8+0] += bf2f((unsigned short)(v.x & 0xffff));
                        a[u*8+1] += bf2f((unsigned short)(v.x >> 16));
                        a[u*8+2] += bf2f((unsigned short)(v.y & 0xffff));
                        a[u*8+3] += bf2f((unsigned short)(v.y >> 16));
                        a[u*8+4] += bf2f((unsigned short)(v.z & 0xffff));
                        a[u*8+5] += bf2f((unsigned short)(v.z >> 16));
                        a[u*8+6] += bf2f((unsigned short)(v.w & 0xffff));
                        a[u*8+7] += bf2f((unsigned short)(v.w >> 16));
                    }
                } else {
                    const float* p = (const float*)e_buf_v + (long)elist[j]*DD + cq;
                    #pragma unroll
                    for (int q = 0; q < 8; ++q) {
                        const float4 v = *(const float4*)(p + q*4);
                        a[q*4+0] += v.x; a[q*4+1] += v.y;
                        a[q*4+2] += v.z; a[q*4+3] += v.w;
                    }
                }
            }
        }
        #pragma unroll
        for (int q = 0; q < 8; ++q) {
            ushort4 o;
            o.x = f2bf(a[q*4+0]); o.y = f2bf(a[q*4+1]);
            o.z = f2bf(a[q*4+2]); o.w = f2bf(a[q*4+3]);
            *(ushort4*)&AnG[r][cq + q*4] = o;
        }
    }

    #pragma unroll
    for (int it = 0; it < 8; ++it) {
        const int i = tid + it*256;
        const int row = i >> 5;
        const int c = (i & 31) * 4;
        float4 v = {0.f, 0.f, 0.f, 0.f};
        if (base + row < NODES) v = *(const float4*)&n_in[(base + row)*DD + c];
        ushort4 o; o.x = f2bf(v.x); o.y = f2bf(v.y); o.z = f2bf(v.z); o.w = f2bf(v.w);
        *(ushort4*)&AnN[row][c] = o;
    }
    __syncthreads();

    f32x4 acc[2][4] = {};
    #pragma unroll
    for (int kt = 0; kt < 8; ++kt) {
        const unsigned short* a0p = (kt < 4) ? &AnN[R0 + ll][kt*32 + lg*8]
                                             : &AnG[R0 + ll][(kt-4)*32 + lg*8];
        const unsigned short* a1p = (kt < 4) ? &AnN[R0 + 16 + ll][kt*32 + lg*8]
                                             : &AnG[R0 + 16 + ll][(kt-4)*32 + lg*8];
        const v8bf a0 = *(const v8bf*)a0p;
        const v8bf a1 = *(const v8bf*)a1p;
        #pragma unroll
        for (int ct = 0; ct < 4; ++ct) {
            const v8bf b = *(const v8bf*)&Wp1[((kt*8 + wc*4 + ct)*64 + lane)*8];
            acc[0][ct] = __builtin_amdgcn_mfma_f32_16x16x32_bf16(a0, b, acc[0][ct], 0, 0, 0);
            acc[1][ct] = __builtin_amdgcn_mfma_f32_16x16x32_bf16(a1, b, acc[1][ct], 0, 0, 0);
        }
    }

    f32x4 s[2], q2[2];
    #pragma unroll
    for (int rt = 0; rt < 2; ++rt) {
        #pragma unroll
        for (int ct = 0; ct < 4; ++ct) acc[rt][ct] += b1v[ct];
        s[rt] = acc[rt][0] + acc[rt][1] + acc[rt][2] + acc[rt][3];
        q2[rt] = acc[rt][0]*acc[rt][0] + acc[rt][1]*acc[rt][1]
               + acc[rt][2]*acc[rt][2] + acc[rt][3]*acc[rt][3];
    }
    #pragma unroll
    for (int off_ = 1; off_ <= 8; off_ <<= 1) {
        #pragma unroll
        for (int rt = 0; rt < 2; ++rt)
            #pragma unroll
            for (int j = 0; j < 4; ++j) {
                s[rt][j] += __shfl_xor(s[rt][j], off_);
                q2[rt][j] += __shfl_xor(q2[rt][j], off_);
            }
    }
    if (ll == 0) {
        #pragma unroll
        for (int rt = 0; rt < 2; ++rt)
            #pragma unroll
            for (int j = 0; j < 4; ++j) {
                red[w][rt*16 + lg*4 + j][0] = s[rt][j];
                red[w][rt*16 + lg*4 + j][1] = q2[rt][j];
            }
    }
    __syncthreads();

    #pragma unroll
    for (int rt = 0; rt < 2; ++rt) {
        #pragma unroll
        for (int j = 0; j < 4; ++j) {
            const int lr = rt*16 + lg*4 + j;
            const float S = red[2*wr][lr][0] + red[2*wr + 1][lr][0];
            const float Q = red[2*wr][lr][1] + red[2*wr + 1][lr][1];
            const float mu = S * (1.0f/DD);
            const float var = Q * (1.0f/DD) - mu*mu;
            const float inv = rsqrtf(var + 1e-5f);
            #pragma unroll
            for (int ct = 0; ct < 4; ++ct) {
                const float hn = (acc[rt][ct][j] - mu) * inv * g1v[ct] + be1v[ct];
                const float sv = hn / (1.0f + __expf(-hn));
                AnG[R0 + lr][C0 + ct*16 + ll] = f2bf(sv);
            }
        }
    }
    __syncthreads();

    f32x4 acc2[2][4] = {};
    #pragma unroll
    for (int kt = 0; kt < 4; ++kt) {
        const v8bf a0 = *(const v8bf*)&AnG[R0 + ll][kt*32 + lg*8];
        const v8bf a1 = *(const v8bf*)&AnG[R0 + 16 + ll][kt*32 + lg*8];
        #pragma unroll
        for (int ct = 0; ct < 4; ++ct) {
            const v8bf b = *(const v8bf*)&Wp2[((kt*8 + wc*4 + ct)*64 + lane)*8];
            acc2[0][ct] = __builtin_amdgcn_mfma_f32_16x16x32_bf16(a0, b, acc2[0][ct], 0, 0, 0);
            acc2[1][ct] = __builtin_amdgcn_mfma_f32_16x16x32_bf16(a1, b, acc2[1][ct], 0, 0, 0);
        }
    }

    #pragma unroll
    for (int rt = 0; rt < 2; ++rt)
        #pragma unroll
        for (int ct = 0; ct < 4; ++ct)
            #pragma unroll
            for (int j = 0; j < 4; ++j) {
                const long grow = base + R0 + rt*16 + lg*4 + j;
                if (grow < NODES) {
                    const int col = C0 + ct*16 + ll;
                    n_out[grow*DD + col] = n_in[grow*DD + col] + acc2[rt][ct][j] + b2v[ct];
                }
            }
}

extern "C" void kernel_launch(void* const* d_in, const int* in_sizes, int n_in,
                              void* d_out, int out_size, void* d_ws, size_t ws_size,
                              hipStream_t stream) {
    const float* node_feat = (const float*)d_in[0];
    const float* edge_attr = (const float*)d_in[1];
    const int*   edge_index= (const int*)d_in[2];
    const float* eW1 = (const float*)d_in[3];
    const float* eb1 = (const float*)d_in[4];
    const float* eg1 = (const float*)d_in[5];
    const float* ebe1= (const float*)d_in[6];
    const float* eW2 = (const float*)d_in[7];
    const float* eb2 = (const float*)d_in[8];
    const float* nW1 = (const float*)d_in[9];
    const float* nb1 = (const float*)d_in[10];
    const float* ng1 = (const float*)d_in[11];
    const float* nbe1= (const float*)d_in[12];
    const float* nW2 = (const float*)d_in[13];
    const float* nb2 = (const float*)d_in[14];

    const int N = NODES, E = EDGES;
    const int* src  = edge_index;
    const int* dstI = edge_index + E;

    float* out_n = (float*)d_out;
    float* out_e = (float*)d_out + (size_t)N * DD;

    // ws: [wp 458752 B][deg 50000][off 50001][cursor 50000][elist 256000] ints
    //     [e1w 65.536 MB bf16 @ 2082816][NG1 25.6 MB bf16 @ 67618944 if fits]
    unsigned short* wp = (unsigned short*)d_ws;
    int* ib     = (int*)((char*)d_ws + 458752);
    int* deg    = ib;
    int* off    = ib + 50000;
    int* cursor = ib + 100001;
    int* elist  = ib + 150001;
    unsigned short* e1w = (unsigned short*)((char*)d_ws + 2082816);
    unsigned short* NG1 = (unsigned short*)((char*)d_ws + 67618944);
    const bool big_ws = ws_size >= (67618944ull + (size_t)NODES*256*2 + 64);

    pack_weights<<<48, 512, 0, stream>>>(eW1, eW2, nW1, nW2, wp);

    hipMemsetAsync(deg, 0, (size_t)N * sizeof(int), stream);
    hist_kernel<<<(E + 255)/256, 256, 0, stream>>>(dstI, deg);
    scan_deg<<<1, 1024, 0, stream>>>(deg, off, cursor);
    place_kernel<<<(E + 255)/256, 256, 0, stream>>>(dstI, cursor, elist);

    const int NB = (N + 63)/64;
    unsigned short* NG0 = (unsigned short*)out_e;   // dead space during layer 0

    // ---- layer 0 ----
    node_proj<<<NB, 256, 0, stream>>>(node_feat, wp + 32768, NG0);
    edge_mlp_ng<true><<<E/64, 256, 0, stream>>>(
        edge_attr, NG0, elist, src, dstI,
        wp, eb1, eg1, ebe1, wp + 98304, eb2, e1w, nullptr);
    node_mlp<true><<<NB, 256, 0, stream>>>(
        node_feat, e1w, off, elist,
        wp + 131072, nb1, ng1, nbe1, wp + 196608, nb2, out_n);

    // ---- layer 1 ----
    if (big_ws) {
        node_proj<<<NB, 256, 0, stream>>>(out_n, wp + 32768 + 32768, NG1);
        edge_mlp_ng<false><<<E/64, 256, 0, stream>>>(
            e1w, NG1, elist, src, dstI,
            wp + 16384, eb1 + DD, eg1 + DD, ebe1 + DD,
            wp + 98304 + 16384, eb2 + DD, e1w /*in-place e2w*/, out_e);
        node_mlp<true><<<NB, 256, 0, stream>>>(
            out_n, e1w, off, elist,
            wp + 131072 + 32768, nb1 + DD, ng1 + DD, nbe1 + DD,
            wp + 196608 + 16384, nb2 + DD, out_n);
    } else {
        edge_mlp_full<<<E/64, 256, 0, stream>>>(
            e1w, out_n, elist, src, dstI,
            wp + 16384, wp + 32768 + 32768,
            eb1 + DD, eg1 + DD, ebe1 + DD,
            wp + 98304 + 16384, eb2 + DD, out_e);
        node_mlp<false><<<NB, 256, 0, stream>>>(
            out_n, out_e, off, elist,
            wp + 131072 + 32768, nb1 + DD, ng1 + DD, nbe1 + DD,
            wp + 196608 + 16384, nb2 + DD, out_n);
    }
}

// Round 7
// 349.270 us; speedup vs baseline: 6.1100x; 1.3232x over previous
//
#include <hip/hip_runtime.h>
#include <hip/hip_bf16.h>

typedef float f32x4 __attribute__((ext_vector_type(4)));
typedef __bf16 v8bf __attribute__((ext_vector_type(8)));

#define DD 128
#define EDGES 256000
#define NODES 50000
#define SCAN_BLOCKS 49   // 49*1024 >= 50000

__device__ __forceinline__ unsigned short f2bf(float f) {
    union { float f; unsigned u; } v; v.f = f;
    unsigned r = v.u + 0x7fffu + ((v.u >> 16) & 1u);
    return (unsigned short)(r >> 16);
}
__device__ __forceinline__ float bf2f(unsigned short u) {
    union { unsigned u; float f; } v; v.u = ((unsigned)u) << 16; return v.f;
}

// ---------------------------------------------------------------------------
// Weight prep. Packed B-fragment layout for a [K x C] matrix:
//   dst[((kt*(C/16)+ct)*64+l)*8+j] = bf16(W[(kt*32+(l>>4)*8+j)*C + ct*16+(l&15)])
// wp layout (ushorts):
//   eW1a: layer*16384 | eWbc: 32768+layer*32768 | eW2: 98304+layer*16384
//   nW1: 131072+layer*32768 | nW2: 196608+layer*16384
// ---------------------------------------------------------------------------
__global__ __launch_bounds__(512)
void pack_weights(const float* __restrict__ eW1, const float* __restrict__ eW2,
                  const float* __restrict__ nW1, const float* __restrict__ nW2,
                  unsigned short* __restrict__ wp)
{
    const int b = blockIdx.x;            // 0..47
    const int layer = b / 24;
    const int u = b % 24;
    const int t = threadIdx.x;
    const int ct0 = t >> 6, l = t & 63;
    const int lg = l >> 4, ll = l & 15;

    if (u < 8 && u >= 4) {
        // eWbc: [128 x 256], Wbc[k][c] = eW1[128 + k + (c>=128?128:0)][c&127]
        const int kt = u - 4;
        const float* W = eW1 + layer*49152;
        unsigned short* dst = wp + 32768 + layer*32768;
        #pragma unroll
        for (int h = 0; h < 2; ++h) {
            const int ct = ct0 + h*8;
            #pragma unroll
            for (int j = 0; j < 8; ++j) {
                const int k = kt*32 + lg*8 + j;
                const int cout = ct*16 + ll;
                const int row = 128 + k + ((cout >= 128) ? 128 : 0);
                const int col = cout & 127;
                dst[((kt*16 + ct)*64 + l)*8 + j] = f2bf(W[row*128 + col]);
            }
        }
        return;
    }
    const float* W; int kt; unsigned short* dst;
    if (u < 4)       { W = eW1 + layer*49152; kt = u;      dst = wp + layer*16384; }
    else if (u < 12) { W = eW2 + layer*16384; kt = u - 8;  dst = wp + 98304 + layer*16384; }
    else if (u < 20) { W = nW1 + layer*32768; kt = u - 12; dst = wp + 131072 + layer*32768; }
    else             { W = nW2 + layer*16384; kt = u - 20; dst = wp + 196608 + layer*16384; }
    #pragma unroll
    for (int j = 0; j < 8; ++j) {
        const int k = kt*32 + lg*8 + j;
        const int c = ct0*16 + ll;
        dst[((kt*8 + ct0)*64 + l)*8 + j] = f2bf(W[k*128 + c]);
    }
}

// ---------------------------------------------------------------------------
// CSR build: histogram -> 3-pass multi-block scan -> placement
// ---------------------------------------------------------------------------
__global__ void hist_kernel(const int* __restrict__ dst, int* __restrict__ deg)
{
    const int i = blockIdx.x * blockDim.x + threadIdx.x;
    if (i < EDGES) atomicAdd(&deg[dst[i]], 1);
}

__global__ __launch_bounds__(256)
void scan_pass1(const int* __restrict__ deg, int* __restrict__ bsum)
{
    __shared__ int ws[256];
    const int b = blockIdx.x, t = threadIdx.x;
    const int base = b*1024 + t*4;
    int s = 0;
    #pragma unroll
    for (int k = 0; k < 4; ++k) {
        const int idx = base + k;
        if (idx < NODES) s += deg[idx];
    }
    ws[t] = s;
    __syncthreads();
    for (int d = 128; d >= 1; d >>= 1) {
        if (t < d) ws[t] += ws[t + d];
        __syncthreads();
    }
    if (t == 0) bsum[b] = ws[0];
}

__global__ __launch_bounds__(64)
void scan_pass2(const int* __restrict__ bsum, int* __restrict__ bbase)
{
    const int t = threadIdx.x;
    const int mine = (t < SCAN_BLOCKS) ? bsum[t] : 0;
    int v = mine;
    #pragma unroll
    for (int d = 1; d < 64; d <<= 1) {
        const int u = __shfl_up(v, d);
        if (t >= d) v += u;
    }
    if (t < SCAN_BLOCKS) bbase[t] = v - mine;   // exclusive
}

__global__ __launch_bounds__(256)
void scan_pass3(const int* __restrict__ deg, const int* __restrict__ bbase,
                int* __restrict__ off, int* __restrict__ cursor)
{
    __shared__ int ws[256];
    const int b = blockIdx.x, t = threadIdx.x;
    const int base = b*1024 + t*4;
    int d4[4]; int s = 0;
    #pragma unroll
    for (int k = 0; k < 4; ++k) {
        const int idx = base + k;
        d4[k] = (idx < NODES) ? deg[idx] : 0;
        s += d4[k];
    }
    ws[t] = s;
    __syncthreads();
    for (int d = 1; d < 256; d <<= 1) {
        const int u = (t >= d) ? ws[t - d] : 0;
        __syncthreads();
        ws[t] += u;
        __syncthreads();
    }
    int run = bbase[b] + ws[t] - s;   // exclusive prefix for this thread's chunk
    #pragma unroll
    for (int k = 0; k < 4; ++k) {
        const int idx = base + k;
        if (idx < NODES) { off[idx] = run; cursor[idx] = run; run += d4[k]; }
    }
    if (b == 0 && t == 0) off[NODES] = EDGES;
}

__global__ void place_kernel(const int* __restrict__ dst, int* __restrict__ cursor,
                             int* __restrict__ elist)
{
    const int i = blockIdx.x * blockDim.x + threadIdx.x;
    if (i < EDGES) {
        const int p = atomicAdd(&cursor[dst[i]], 1);
        elist[p] = i;
    }
}

// ---------------------------------------------------------------------------
// Node projection: NG[v] = bf16(n[v] @ Wbc)  -> [NODES x 256] bf16
// ---------------------------------------------------------------------------
__global__ __launch_bounds__(256)
void node_proj(const float* __restrict__ n,
               const unsigned short* __restrict__ Wbc,
               unsigned short* __restrict__ NG)
{
    __shared__ __align__(16) unsigned short A[64][136];
    const int tid = threadIdx.x;
    const long base = (long)blockIdx.x * 64;

    #pragma unroll
    for (int it = 0; it < 8; ++it) {
        const int i = tid + it*256;
        const int row = i >> 5;
        const int c = (i & 31) * 4;
        float4 v = {0.f, 0.f, 0.f, 0.f};
        if (base + row < NODES) v = *(const float4*)&n[(base + row)*DD + c];
        ushort4 o; o.x = f2bf(v.x); o.y = f2bf(v.y); o.z = f2bf(v.z); o.w = f2bf(v.w);
        *(ushort4*)&A[row][c] = o;
    }
    __syncthreads();

    const int lane = tid & 63, w = tid >> 6;
    const int wr = w >> 1, wc = w & 1;
    const int R0 = wr*32, C0w = wc*128;
    const int lg = lane >> 4, ll = lane & 15;

    f32x4 acc[2][8] = {};
    #pragma unroll
    for (int kt = 0; kt < 4; ++kt) {
        const v8bf a0 = *(const v8bf*)&A[R0 + ll][kt*32 + lg*8];
        const v8bf a1 = *(const v8bf*)&A[R0 + 16 + ll][kt*32 + lg*8];
        #pragma unroll
        for (int ct = 0; ct < 8; ++ct) {
            const v8bf b = *(const v8bf*)&Wbc[((kt*16 + wc*8 + ct)*64 + lane)*8];
            acc[0][ct] = __builtin_amdgcn_mfma_f32_16x16x32_bf16(a0, b, acc[0][ct], 0, 0, 0);
            acc[1][ct] = __builtin_amdgcn_mfma_f32_16x16x32_bf16(a1, b, acc[1][ct], 0, 0, 0);
        }
    }

    #pragma unroll
    for (int rt = 0; rt < 2; ++rt)
        #pragma unroll
        for (int ct = 0; ct < 8; ++ct)
            #pragma unroll
            for (int j = 0; j < 4; ++j) {
                const long grow = base + R0 + rt*16 + lg*4 + j;
                if (grow < NODES)
                    NG[grow*256 + C0w + ct*16 + ll] = f2bf(acc[rt][ct][j]);
            }
}

// ---------------------------------------------------------------------------
// Edge MLP with precomputed node projections (dst-sorted edge order).
// ---------------------------------------------------------------------------
template <bool L0>
__global__ __launch_bounds__(256, 4)
void edge_mlp_ng(const void* __restrict__ e_in_v,
                 const unsigned short* __restrict__ NG,
                 const int* __restrict__ elist,
                 const int* __restrict__ srcA, const int* __restrict__ dstA,
                 const unsigned short* __restrict__ Wa,
                 const float* __restrict__ b1, const float* __restrict__ g1,
                 const float* __restrict__ be1,
                 const unsigned short* __restrict__ Wp2,
                 const float* __restrict__ b2,
                 unsigned short* __restrict__ ePw,
                 float* __restrict__ e_out)
{
    __shared__ __align__(16) unsigned short AeE[64][136];
    __shared__ __align__(16) unsigned short Sl[64][136];
    __shared__ float red[4][32][2];
    __shared__ int eidx[64], sidx[64], didx[64];

    const int tid = threadIdx.x;
    const long base = (long)blockIdx.x * 64;

    if (tid < 64) {
        const int i = elist[base + tid];
        eidx[tid] = i; sidx[tid] = srcA[i]; didx[tid] = dstA[i];
    }
    __syncthreads();

    const int lane = tid & 63, w = tid >> 6;
    const int wr = w >> 1, wc = w & 1;
    const int R0 = wr*32, C0 = wc*64;
    const int lg = lane >> 4, ll = lane & 15;

    // stage e tile
    if constexpr (L0) {
        const float* e_in = (const float*)e_in_v;
        #pragma unroll
        for (int it = 0; it < 8; ++it) {
            const int i = tid + it*256;
            const int row = i >> 5;
            const int c = (i & 31) * 4;
            const float4 v = *(const float4*)&e_in[(long)eidx[row]*DD + c];
            ushort4 o; o.x = f2bf(v.x); o.y = f2bf(v.y); o.z = f2bf(v.z); o.w = f2bf(v.w);
            *(ushort4*)&AeE[row][c] = o;
        }
    } else {
        const unsigned short* e_in = (const unsigned short*)e_in_v;
        #pragma unroll
        for (int it = 0; it < 4; ++it) {
            const int i = tid + it*256;
            const int row = i >> 4;
            const int c = (i & 15) * 8;
            *(uint4*)&AeE[row][c] = *(const uint4*)&e_in[(base + row)*DD + c];
        }
    }
    __syncthreads();

    float b1v[4], g1v[4], be1v[4], b2v[4];
    #pragma unroll
    for (int ct = 0; ct < 4; ++ct) {
        const int c = C0 + ct*16 + ll;
        b1v[ct] = b1[c]; g1v[ct] = g1[c]; be1v[ct] = be1[c]; b2v[ct] = b2[c];
    }

    // GEMM1a: eP @ W1a (K=128)
    f32x4 acc[2][4] = {};
    #pragma unroll
    for (int kt = 0; kt < 4; ++kt) {
        const v8bf a0 = *(const v8bf*)&AeE[R0 + ll][kt*32 + lg*8];
        const v8bf a1 = *(const v8bf*)&AeE[R0 + 16 + ll][kt*32 + lg*8];
        #pragma unroll
        for (int ct = 0; ct < 4; ++ct) {
            const v8bf b = *(const v8bf*)&Wa[((kt*8 + wc*4 + ct)*64 + lane)*8];
            acc[0][ct] = __builtin_amdgcn_mfma_f32_16x16x32_bf16(a0, b, acc[0][ct], 0, 0, 0);
            acc[1][ct] = __builtin_amdgcn_mfma_f32_16x16x32_bf16(a1, b, acc[1][ct], 0, 0, 0);
        }
    }

    // + NG[src][col] + NG[dst][128+col]
    #pragma unroll
    for (int rt = 0; rt < 2; ++rt) {
        #pragma unroll
        for (int j = 0; j < 4; ++j) {
            const int lr = rt*16 + lg*4 + j;
            const long sid = sidx[R0 + lr];
            const long did = didx[R0 + lr];
            const unsigned short* pb = NG + sid*256 + C0 + ll;
            const unsigned short* pc = NG + did*256 + 128 + C0 + ll;
            #pragma unroll
            for (int ct = 0; ct < 4; ++ct)
                acc[rt][ct][j] += bf2f(pb[ct*16]) + bf2f(pc[ct*16]);
        }
    }

    // bias + LN stats
    f32x4 s[2], q[2];
    #pragma unroll
    for (int rt = 0; rt < 2; ++rt) {
        #pragma unroll
        for (int ct = 0; ct < 4; ++ct) acc[rt][ct] += b1v[ct];
        s[rt] = acc[rt][0] + acc[rt][1] + acc[rt][2] + acc[rt][3];
        q[rt] = acc[rt][0]*acc[rt][0] + acc[rt][1]*acc[rt][1]
              + acc[rt][2]*acc[rt][2] + acc[rt][3]*acc[rt][3];
    }
    #pragma unroll
    for (int off = 1; off <= 8; off <<= 1) {
        #pragma unroll
        for (int rt = 0; rt < 2; ++rt)
            #pragma unroll
            for (int j = 0; j < 4; ++j) {
                s[rt][j] += __shfl_xor(s[rt][j], off);
                q[rt][j] += __shfl_xor(q[rt][j], off);
            }
    }
    if (ll == 0) {
        #pragma unroll
        for (int rt = 0; rt < 2; ++rt)
            #pragma unroll
            for (int j = 0; j < 4; ++j) {
                red[w][rt*16 + lg*4 + j][0] = s[rt][j];
                red[w][rt*16 + lg*4 + j][1] = q[rt][j];
            }
    }
    __syncthreads();

    // LN + SiLU -> Sl
    #pragma unroll
    for (int rt = 0; rt < 2; ++rt) {
        #pragma unroll
        for (int j = 0; j < 4; ++j) {
            const int lr = rt*16 + lg*4 + j;
            const float S = red[2*wr][lr][0] + red[2*wr + 1][lr][0];
            const float Q = red[2*wr][lr][1] + red[2*wr + 1][lr][1];
            const float mu = S * (1.0f/DD);
            const float var = Q * (1.0f/DD) - mu*mu;
            const float inv = rsqrtf(var + 1e-5f);
            #pragma unroll
            for (int ct = 0; ct < 4; ++ct) {
                const float hn = (acc[rt][ct][j] - mu) * inv * g1v[ct] + be1v[ct];
                const float sv = hn / (1.0f + __expf(-hn));
                Sl[R0 + lr][C0 + ct*16 + ll] = f2bf(sv);
            }
        }
    }
    __syncthreads();

    // GEMM2
    f32x4 acc2[2][4] = {};
    #pragma unroll
    for (int kt = 0; kt < 4; ++kt) {
        const v8bf a0 = *(const v8bf*)&Sl[R0 + ll][kt*32 + lg*8];
        const v8bf a1 = *(const v8bf*)&Sl[R0 + 16 + ll][kt*32 + lg*8];
        #pragma unroll
        for (int ct = 0; ct < 4; ++ct) {
            const v8bf b = *(const v8bf*)&Wp2[((kt*8 + wc*4 + ct)*64 + lane)*8];
            acc2[0][ct] = __builtin_amdgcn_mfma_f32_16x16x32_bf16(a0, b, acc2[0][ct], 0, 0, 0);
            acc2[1][ct] = __builtin_amdgcn_mfma_f32_16x16x32_bf16(a1, b, acc2[1][ct], 0, 0, 0);
        }
    }

    // residual + store
    #pragma unroll
    for (int rt = 0; rt < 2; ++rt)
        #pragma unroll
        for (int ct = 0; ct < 4; ++ct)
            #pragma unroll
            for (int j = 0; j < 4; ++j) {
                const int lr = rt*16 + lg*4 + j;
                const int col = C0 + ct*16 + ll;
                const float v = bf2f(AeE[R0 + lr][col]) + acc2[rt][ct][j] + b2v[ct];
                ePw[(base + R0 + lr)*DD + col] = f2bf(v);
                if constexpr (!L0)
                    e_out[(long)eidx[R0 + lr]*DD + col] = v;
            }
}

// ---------------------------------------------------------------------------
// Full-K edge MLP fallback (layer 1 without NG1 space)
// ---------------------------------------------------------------------------
__global__ __launch_bounds__(256, 4)
void edge_mlp_full(const unsigned short* __restrict__ e_in,
                   const float* __restrict__ nf,
                   const int* __restrict__ elist,
                   const int* __restrict__ srcA, const int* __restrict__ dstA,
                   const unsigned short* __restrict__ Wa,
                   const unsigned short* __restrict__ Wbc,
                   const float* __restrict__ b1, const float* __restrict__ g1,
                   const float* __restrict__ be1,
                   const unsigned short* __restrict__ Wp2,
                   const float* __restrict__ b2, float* __restrict__ e_out)
{
    __shared__ __align__(16) unsigned short AeE[64][136];
    __shared__ __align__(16) unsigned short AeG[64][132];
    __shared__ float red[4][32][2];
    __shared__ int eidx[64], sidx[64], didx[64];

    const int tid = threadIdx.x;
    const long base = (long)blockIdx.x * 64;

    if (tid < 64) {
        const int i = elist[base + tid];
        eidx[tid] = i; sidx[tid] = srcA[i]; didx[tid] = dstA[i];
    }

    const int lane = tid & 63, w = tid >> 6;
    const int wr = w >> 1, wc = w & 1;
    const int R0 = wr*32, C0 = wc*64;
    const int lg = lane >> 4, ll = lane & 15;

    #pragma unroll
    for (int it = 0; it < 4; ++it) {
        const int i = tid + it*256;
        const int row = i >> 4;
        const int c = (i & 15) * 8;
        *(uint4*)&AeE[row][c] = *(const uint4*)&e_in[(base + row)*DD + c];
    }
    __syncthreads();

    #pragma unroll
    for (int it = 0; it < 8; ++it) {
        const int i = tid + it*256;
        const int row = i >> 5;
        const int c = (i & 31) * 4;
        const float4 v = *(const float4*)&nf[(long)sidx[row]*DD + c];
        ushort4 o; o.x = f2bf(v.x); o.y = f2bf(v.y); o.z = f2bf(v.z); o.w = f2bf(v.w);
        *(ushort4*)&AeG[row][c] = o;
    }
    float4 dreg[8];
    #pragma unroll
    for (int it = 0; it < 8; ++it) {
        const int i = tid + it*256;
        const int row = i >> 5;
        const int c = (i & 31) * 4;
        dreg[it] = *(const float4*)&nf[(long)didx[row]*DD + c];
    }
    __syncthreads();

    float b1v[4], g1v[4], be1v[4], b2v[4];
    #pragma unroll
    for (int ct = 0; ct < 4; ++ct) {
        const int c = C0 + ct*16 + ll;
        b1v[ct] = b1[c]; g1v[ct] = g1[c]; be1v[ct] = be1[c]; b2v[ct] = b2[c];
    }

    f32x4 acc[2][4] = {};
    #pragma unroll
    for (int kt = 0; kt < 8; ++kt) {
        const unsigned short* a0p = (kt < 4) ? &AeE[R0 + ll][kt*32 + lg*8]
                                             : &AeG[R0 + ll][(kt-4)*32 + lg*8];
        const unsigned short* a1p = (kt < 4) ? &AeE[R0 + 16 + ll][kt*32 + lg*8]
                                             : &AeG[R0 + 16 + ll][(kt-4)*32 + lg*8];
        const v8bf a0 = *(const v8bf*)a0p;
        const v8bf a1 = *(const v8bf*)a1p;
        #pragma unroll
        for (int ct = 0; ct < 4; ++ct) {
            const v8bf b = (kt < 4)
                ? *(const v8bf*)&Wa[((kt*8 + wc*4 + ct)*64 + lane)*8]
                : *(const v8bf*)&Wbc[(((kt-4)*16 + wc*4 + ct)*64 + lane)*8];
            acc[0][ct] = __builtin_amdgcn_mfma_f32_16x16x32_bf16(a0, b, acc[0][ct], 0, 0, 0);
            acc[1][ct] = __builtin_amdgcn_mfma_f32_16x16x32_bf16(a1, b, acc[1][ct], 0, 0, 0);
        }
    }
    __syncthreads();

    #pragma unroll
    for (int it = 0; it < 8; ++it) {
        const int i = tid + it*256;
        const int row = i >> 5;
        const int c = (i & 31) * 4;
        ushort4 o; o.x = f2bf(dreg[it].x); o.y = f2bf(dreg[it].y);
        o.z = f2bf(dreg[it].z); o.w = f2bf(dreg[it].w);
        *(ushort4*)&AeG[row][c] = o;
    }
    __syncthreads();

    #pragma unroll
    for (int kt = 0; kt < 4; ++kt) {
        const v8bf a0 = *(const v8bf*)&AeG[R0 + ll][kt*32 + lg*8];
        const v8bf a1 = *(const v8bf*)&AeG[R0 + 16 + ll][kt*32 + lg*8];
        #pragma unroll
        for (int ct = 0; ct < 4; ++ct) {
            const v8bf b = *(const v8bf*)&Wbc[((kt*16 + 8 + wc*4 + ct)*64 + lane)*8];
            acc[0][ct] = __builtin_amdgcn_mfma_f32_16x16x32_bf16(a0, b, acc[0][ct], 0, 0, 0);
            acc[1][ct] = __builtin_amdgcn_mfma_f32_16x16x32_bf16(a1, b, acc[1][ct], 0, 0, 0);
        }
    }

    f32x4 s[2], q[2];
    #pragma unroll
    for (int rt = 0; rt < 2; ++rt) {
        #pragma unroll
        for (int ct = 0; ct < 4; ++ct) acc[rt][ct] += b1v[ct];
        s[rt] = acc[rt][0] + acc[rt][1] + acc[rt][2] + acc[rt][3];
        q[rt] = acc[rt][0]*acc[rt][0] + acc[rt][1]*acc[rt][1]
              + acc[rt][2]*acc[rt][2] + acc[rt][3]*acc[rt][3];
    }
    #pragma unroll
    for (int off = 1; off <= 8; off <<= 1) {
        #pragma unroll
        for (int rt = 0; rt < 2; ++rt)
            #pragma unroll
            for (int j = 0; j < 4; ++j) {
                s[rt][j] += __shfl_xor(s[rt][j], off);
                q[rt][j] += __shfl_xor(q[rt][j], off);
            }
    }
    if (ll == 0) {
        #pragma unroll
        for (int rt = 0; rt < 2; ++rt)
            #pragma unroll
            for (int j = 0; j < 4; ++j) {
                red[w][rt*16 + lg*4 + j][0] = s[rt][j];
                red[w][rt*16 + lg*4 + j][1] = q[rt][j];
            }
    }
    __syncthreads();

    #pragma unroll
    for (int rt = 0; rt < 2; ++rt) {
        #pragma unroll
        for (int j = 0; j < 4; ++j) {
            const int lr = rt*16 + lg*4 + j;
            const float S = red[2*wr][lr][0] + red[2*wr + 1][lr][0];
            const float Q = red[2*wr][lr][1] + red[2*wr + 1][lr][1];
            const float mu = S * (1.0f/DD);
            const float var = Q * (1.0f/DD) - mu*mu;
            const float inv = rsqrtf(var + 1e-5f);
            #pragma unroll
            for (int ct = 0; ct < 4; ++ct) {
                const float hn = (acc[rt][ct][j] - mu) * inv * g1v[ct] + be1v[ct];
                const float sv = hn / (1.0f + __expf(-hn));
                AeG[R0 + lr][C0 + ct*16 + ll] = f2bf(sv);
            }
        }
    }
    __syncthreads();

    f32x4 acc2[2][4] = {};
    #pragma unroll
    for (int kt = 0; kt < 4; ++kt) {
        const v8bf a0 = *(const v8bf*)&AeG[R0 + ll][kt*32 + lg*8];
        const v8bf a1 = *(const v8bf*)&AeG[R0 + 16 + ll][kt*32 + lg*8];
        #pragma unroll
        for (int ct = 0; ct < 4; ++ct) {
            const v8bf b = *(const v8bf*)&Wp2[((kt*8 + wc*4 + ct)*64 + lane)*8];
            acc2[0][ct] = __builtin_amdgcn_mfma_f32_16x16x32_bf16(a0, b, acc2[0][ct], 0, 0, 0);
            acc2[1][ct] = __builtin_amdgcn_mfma_f32_16x16x32_bf16(a1, b, acc2[1][ct], 0, 0, 0);
        }
    }

    #pragma unroll
    for (int rt = 0; rt < 2; ++rt)
        #pragma unroll
        for (int ct = 0; ct < 4; ++ct)
            #pragma unroll
            for (int j = 0; j < 4; ++j) {
                const int lr = rt*16 + lg*4 + j;
                const int col = C0 + ct*16 + ll;
                const float v = bf2f(AeE[R0 + lr][col]) + acc2[rt][ct][j] + b2v[ct];
                e_out[(long)eidx[R0 + lr]*DD + col] = v;
            }
}

// ---------------------------------------------------------------------------
// Node MLP with CSR gather-aggregate.
// ---------------------------------------------------------------------------
template <bool SEQ>
__global__ __launch_bounds__(256)
void node_mlp(const float* n_in, const void* __restrict__ e_buf_v,
              const int* __restrict__ off, const int* __restrict__ elist,
              const unsigned short* __restrict__ Wp1,
              const float* __restrict__ b1, const float* __restrict__ g1,
              const float* __restrict__ be1,
              const unsigned short* __restrict__ Wp2,
              const float* __restrict__ b2, float* n_out)
{
    __shared__ __align__(16) unsigned short AnN[64][136];
    __shared__ __align__(16) unsigned short AnG[64][136];
    __shared__ float red[4][32][2];

    const int tid = threadIdx.x;
    const long base = (long)blockIdx.x * 64;

    const int lane = tid & 63, w = tid >> 6;
    const int wr = w >> 1, wc = w & 1;
    const int R0 = wr*32, C0 = wc*64;
    const int lg = lane >> 4, ll = lane & 15;

    float b1v[4], g1v[4], be1v[4], b2v[4];
    #pragma unroll
    for (int ct = 0; ct < 4; ++ct) {
        const int c = C0 + ct*16 + ll;
        b1v[ct] = b1[c]; g1v[ct] = g1[c]; be1v[ct] = be1[c]; b2v[ct] = b2[c];
    }

    // gather-aggregate: 4 threads/row x 32 cols
    {
        const int r  = tid >> 2;
        const int cq = (tid & 3) * 32;
        const long row = base + r;
        float a[32];
        #pragma unroll
        for (int q = 0; q < 32; ++q) a[q] = 0.f;
        if (row < NODES) {
            const int jb = off[row], je = off[row + 1];
            for (int j = jb; j < je; ++j) {
                if constexpr (SEQ) {
                    const unsigned short* p = (const unsigned short*)e_buf_v + (long)j*DD + cq;
                    #pragma unroll
                    for (int u = 0; u < 4; ++u) {
                        const uint4 v = *(const uint4*)(p + u*8);
                        a[u*8+0] += bf2f((unsigned short)(v.x & 0xffff));
                        a[u*8+1] += bf2f((unsigned short)(v.x >> 16));
                        a[u*8+2] += bf2f((unsigned short)(v.y & 0xffff));
                        a[u*8+3] += bf2f((unsigned short)(v.y >> 16));
                        a[u*8+4] += bf2f((unsigned short)(v.z & 0xffff));
                        a[u*8+5] += bf2f((unsigned short)(v.z >> 16));
                        a[u*8+6] += bf2f((unsigned short)(v.w & 0xffff));
                        a[u*8+7] += bf2f((unsigned short)(v.w >> 16));
                    }
                } else {
                    const float* p = (const float*)e_buf_v + (long)elist[j]*DD + cq;
                    #pragma unroll
                    for (int q = 0; q < 8; ++q) {
                        const float4 v = *(const float4*)(p + q*4);
                        a[q*4+0] += v.x; a[q*4+1] += v.y;
                        a[q*4+2] += v.z; a[q*4+3] += v.w;
                    }
                }
            }
        }
        #pragma unroll
        for (int q = 0; q < 8; ++q) {
            ushort4 o;
            o.x = f2bf(a[q*4+0]); o.y = f2bf(a[q*4+1]);
            o.z = f2bf(a[q*4+2]); o.w = f2bf(a[q*4+3]);
            *(ushort4*)&AnG[r][cq + q*4] = o;
        }
    }

    #pragma unroll
    for (int it = 0; it < 8; ++it) {
        const int i = tid + it*256;
        const int row = i >> 5;
        const int c = (i & 31) * 4;
        float4 v = {0.f, 0.f, 0.f, 0.f};
        if (base + row < NODES) v = *(const float4*)&n_in[(base + row)*DD + c];
        ushort4 o; o.x = f2bf(v.x); o.y = f2bf(v.y); o.z = f2bf(v.z); o.w = f2bf(v.w);
        *(ushort4*)&AnN[row][c] = o;
    }
    __syncthreads();

    f32x4 acc[2][4] = {};
    #pragma unroll
    for (int kt = 0; kt < 8; ++kt) {
        const unsigned short* a0p = (kt < 4) ? &AnN[R0 + ll][kt*32 + lg*8]
                                             : &AnG[R0 + ll][(kt-4)*32 + lg*8];
        const unsigned short* a1p = (kt < 4) ? &AnN[R0 + 16 + ll][kt*32 + lg*8]
                                             : &AnG[R0 + 16 + ll][(kt-4)*32 + lg*8];
        const v8bf a0 = *(const v8bf*)a0p;
        const v8bf a1 = *(const v8bf*)a1p;
        #pragma unroll
        for (int ct = 0; ct < 4; ++ct) {
            const v8bf b = *(const v8bf*)&Wp1[((kt*8 + wc*4 + ct)*64 + lane)*8];
            acc[0][ct] = __builtin_amdgcn_mfma_f32_16x16x32_bf16(a0, b, acc[0][ct], 0, 0, 0);
            acc[1][ct] = __builtin_amdgcn_mfma_f32_16x16x32_bf16(a1, b, acc[1][ct], 0, 0, 0);
        }
    }

    f32x4 s[2], q2[2];
    #pragma unroll
    for (int rt = 0; rt < 2; ++rt) {
        #pragma unroll
        for (int ct = 0; ct < 4; ++ct) acc[rt][ct] += b1v[ct];
        s[rt] = acc[rt][0] + acc[rt][1] + acc[rt][2] + acc[rt][3];
        q2[rt] = acc[rt][0]*acc[rt][0] + acc[rt][1]*acc[rt][1]
               + acc[rt][2]*acc[rt][2] + acc[rt][3]*acc[rt][3];
    }
    #pragma unroll
    for (int off_ = 1; off_ <= 8; off_ <<= 1) {
        #pragma unroll
        for (int rt = 0; rt < 2; ++rt)
            #pragma unroll
            for (int j = 0; j < 4; ++j) {
                s[rt][j] += __shfl_xor(s[rt][j], off_);
                q2[rt][j] += __shfl_xor(q2[rt][j], off_);
            }
    }
    if (ll == 0) {
        #pragma unroll
        for (int rt = 0; rt < 2; ++rt)
            #pragma unroll
            for (int j = 0; j < 4; ++j) {
                red[w][rt*16 + lg*4 + j][0] = s[rt][j];
                red[w][rt*16 + lg*4 + j][1] = q2[rt][j];
            }
    }
    __syncthreads();

    #pragma unroll
    for (int rt = 0; rt < 2; ++rt) {
        #pragma unroll
        for (int j = 0; j < 4; ++j) {
            const int lr = rt*16 + lg*4 + j;
            const float S = red[2*wr][lr][0] + red[2*wr + 1][lr][0];
            const float Q = red[2*wr][lr][1] + red[2*wr + 1][lr][1];
            const float mu = S * (1.0f/DD);
            const float var = Q * (1.0f/DD) - mu*mu;
            const float inv = rsqrtf(var + 1e-5f);
            #pragma unroll
            for (int ct = 0; ct < 4; ++ct) {
                const float hn = (acc[rt][ct][j] - mu) * inv * g1v[ct] + be1v[ct];
                const float sv = hn / (1.0f + __expf(-hn));
                AnG[R0 + lr][C0 + ct*16 + ll] = f2bf(sv);
            }
        }
    }
    __syncthreads();

    f32x4 acc2[2][4] = {};
    #pragma unroll
    for (int kt = 0; kt < 4; ++kt) {
        const v8bf a0 = *(const v8bf*)&AnG[R0 + ll][kt*32 + lg*8];
        const v8bf a1 = *(const v8bf*)&AnG[R0 + 16 + ll][kt*32 + lg*8];
        #pragma unroll
        for (int ct = 0; ct < 4; ++ct) {
            const v8bf b = *(const v8bf*)&Wp2[((kt*8 + wc*4 + ct)*64 + lane)*8];
            acc2[0][ct] = __builtin_amdgcn_mfma_f32_16x16x32_bf16(a0, b, acc2[0][ct], 0, 0, 0);
            acc2[1][ct] = __builtin_amdgcn_mfma_f32_16x16x32_bf16(a1, b, acc2[1][ct], 0, 0, 0);
        }
    }

    #pragma unroll
    for (int rt = 0; rt < 2; ++rt)
        #pragma unroll
        for (int ct = 0; ct < 4; ++ct)
            #pragma unroll
            for (int j = 0; j < 4; ++j) {
                const long grow = base + R0 + rt*16 + lg*4 + j;
                if (grow < NODES) {
                    const int col = C0 + ct*16 + ll;
                    n_out[grow*DD + col] = n_in[grow*DD + col] + acc2[rt][ct][j] + b2v[ct];
                }
            }
}

extern "C" void kernel_launch(void* const* d_in, const int* in_sizes, int n_in,
                              void* d_out, int out_size, void* d_ws, size_t ws_size,
                              hipStream_t stream) {
    const float* node_feat = (const float*)d_in[0];
    const float* edge_attr = (const float*)d_in[1];
    const int*   edge_index= (const int*)d_in[2];
    const float* eW1 = (const float*)d_in[3];
    const float* eb1 = (const float*)d_in[4];
    const float* eg1 = (const float*)d_in[5];
    const float* ebe1= (const float*)d_in[6];
    const float* eW2 = (const float*)d_in[7];
    const float* eb2 = (const float*)d_in[8];
    const float* nW1 = (const float*)d_in[9];
    const float* nb1 = (const float*)d_in[10];
    const float* ng1 = (const float*)d_in[11];
    const float* nbe1= (const float*)d_in[12];
    const float* nW2 = (const float*)d_in[13];
    const float* nb2 = (const float*)d_in[14];

    const int N = NODES, E = EDGES;
    const int* src  = edge_index;
    const int* dstI = edge_index + E;

    float* out_n = (float*)d_out;
    float* out_e = (float*)d_out + (size_t)N * DD;

    // ws: [wp 458752 B]
    //     [ints @458752: deg 50000 | off 50001 | cursor 50000 | elist 256000 |
    //                    bsum 64 | bbase 64]  (ends at 2083268 B)
    //     [e1w 65.536 MB bf16 @ 2083840]
    //     [NG1 25.6  MB bf16 @ 67619840, if ws allows]
    unsigned short* wp = (unsigned short*)d_ws;
    int* ib     = (int*)((char*)d_ws + 458752);
    int* deg    = ib;
    int* off    = ib + 50000;
    int* cursor = ib + 100001;
    int* elist  = ib + 150001;
    int* bsum   = ib + 406001;
    int* bbase  = ib + 406065;
    unsigned short* e1w = (unsigned short*)((char*)d_ws + 2083840);
    unsigned short* NG1 = (unsigned short*)((char*)d_ws + 67619840);
    const bool big_ws = ws_size >= (67619840ull + (size_t)NODES*256*2 + 64);

    pack_weights<<<48, 512, 0, stream>>>(eW1, eW2, nW1, nW2, wp);

    hipMemsetAsync(deg, 0, (size_t)N * sizeof(int), stream);
    hist_kernel<<<(E + 255)/256, 256, 0, stream>>>(dstI, deg);
    scan_pass1<<<SCAN_BLOCKS, 256, 0, stream>>>(deg, bsum);
    scan_pass2<<<1, 64, 0, stream>>>(bsum, bbase);
    scan_pass3<<<SCAN_BLOCKS, 256, 0, stream>>>(deg, bbase, off, cursor);
    place_kernel<<<(E + 255)/256, 256, 0, stream>>>(dstI, cursor, elist);

    const int NB = (N + 63)/64;
    unsigned short* NG0 = (unsigned short*)out_e;   // dead space during layer 0

    // ---- layer 0 ----
    node_proj<<<NB, 256, 0, stream>>>(node_feat, wp + 32768, NG0);
    edge_mlp_ng<true><<<E/64, 256, 0, stream>>>(
        edge_attr, NG0, elist, src, dstI,
        wp, eb1, eg1, ebe1, wp + 98304, eb2, e1w, nullptr);
    node_mlp<true><<<NB, 256, 0, stream>>>(
        node_feat, e1w, off, elist,
        wp + 131072, nb1, ng1, nbe1, wp + 196608, nb2, out_n);

    // ---- layer 1 ----
    if (big_ws) {
        node_proj<<<NB, 256, 0, stream>>>(out_n, wp + 32768 + 32768, NG1);
        edge_mlp_ng<false><<<E/64, 256, 0, stream>>>(
            e1w, NG1, elist, src, dstI,
            wp + 16384, eb1 + DD, eg1 + DD, ebe1 + DD,
            wp + 98304 + 16384, eb2 + DD, e1w /*in-place e2w*/, out_e);
        node_mlp<true><<<NB, 256, 0, stream>>>(
            out_n, e1w, off, elist,
            wp + 131072 + 32768, nb1 + DD, ng1 + DD, nbe1 + DD,
            wp + 196608 + 16384, nb2 + DD, out_n);
    } else {
        edge_mlp_full<<<E/64, 256, 0, stream>>>(
            e1w, out_n, elist, src, dstI,
            wp + 16384, wp + 32768 + 32768,
            eb1 + DD, eg1 + DD, ebe1 + DD,
            wp + 98304 + 16384, eb2 + DD, out_e);
        node_mlp<false><<<NB, 256, 0, stream>>>(
            out_n, out_e, off, elist,
            wp + 131072 + 32768, nb1 + DD, ng1 + DD, nbe1 + DD,
            wp + 196608 + 16384, nb2 + DD, out_n);
    }
}